// Round 1
// 1475.091 us; speedup vs baseline: 1.0093x; 1.0093x over previous
//
#include <hip/hip_runtime.h>
#include <hip/hip_fp16.h>

typedef _Float16 f16;
typedef _Float16 f16x8 __attribute__((ext_vector_type(8)));
typedef _Float16 f16x4 __attribute__((ext_vector_type(4)));
typedef float f32x4 __attribute__((ext_vector_type(4)));

// Problem constants
#define BATCH 64
#define NTOK 785          // 1 + 28*28
#define CDIM 768
#define NHEAD 12
#define HDIM 64
#define ANUM 49
#define WIN 28
#define MROWS (BATCH * NTOK)   // 50240

// ---------------- workspace layout (bytes) ----------------
#define SZ_Q   77168640ULL                 // (B*H*N*64) halves
#define OFF_Q  0ULL
#define OFF_K  (OFF_Q + SZ_Q)
#define OFF_V  (OFF_K + SZ_Q)
#define OFF_Y  (OFF_V + SZ_Q)
#define OFF_VT (OFF_Y + SZ_Q)              // V transposed: (bh, d=64, n=800) f16
#define SZ_VT  78643200ULL
#define OFF_P  (OFF_VT + SZ_VT)            // P1 (bh,64,800) / P2 (bh,800,64) f16; also X16 / WP16 overlay
#define SZ_P   78643200ULL
#define OFF_AG (OFF_P + SZ_P)              // agent16: (bh, 64, 64) f16, scaled by 0.125
#define SZ_AG  6291456ULL
#define OFF_AVT (OFF_AG + SZ_AG)           // agentv^T: (bh, d=64, a=64) f16; also W16 overlay
#define OFF_B1 (OFF_AVT + SZ_AG)
#define SZ_B   1846320ULL
#define OFF_B2 (OFF_B1 + SZ_B)
// total ~482 MB (overlays add nothing)

#define GLL(g, l) __builtin_amdgcn_global_load_lds( \
    (const __attribute__((address_space(1))) void*)(g), \
    (__attribute__((address_space(3))) void*)(l), 16, 0, 0)

// ---------------- fp32 -> fp16 conversion (x4 vectorized) -------------------
__global__ void cvt_kernel(const float* __restrict__ s, f16* __restrict__ d, int n4) {
    int i = blockIdx.x * 256 + threadIdx.x;
    if (i >= n4) return;
    float4 v = ((const float4*)s)[i];
    f16x4 o = {(f16)v.x, (f16)v.y, (f16)v.z, (f16)v.w};
    ((f16x4*)d)[i] = o;
}

// ---------------- bilinear (jax.image.resize, half-pixel centers, 7->28) ----
__device__ __forceinline__ float bilin7(const float* __restrict__ t, int y, int x) {
    float fy = 0.25f * (float)y - 0.375f;
    float fx = 0.25f * (float)x - 0.375f;
    int y0 = (int)floorf(fy);
    int x0 = (int)floorf(fx);
    float wy = fy - (float)y0, wx = fx - (float)x0;
    int y0c = max(0, min(6, y0)),     y1c = max(0, min(6, y0 + 1));
    int x0c = max(0, min(6, x0)),     x1c = max(0, min(6, x0 + 1));
    float v00 = t[y0c * 7 + x0c], v01 = t[y0c * 7 + x1c];
    float v10 = t[y1c * 7 + x0c], v11 = t[y1c * 7 + x1c];
    return (1.f - wy) * ((1.f - wx) * v00 + wx * v01) +
           wy        * ((1.f - wx) * v10 + wx * v11);
}

// ---------------- bias kernel: builds bias1[h][a][n] and bias2[h][n][a] -----
__global__ void bias_kernel(const float* __restrict__ an, const float* __restrict__ ah,
                            const float* __restrict__ aw, const float* __restrict__ ac,
                            const float* __restrict__ na, const float* __restrict__ ha,
                            const float* __restrict__ wa, const float* __restrict__ ca,
                            float* __restrict__ bias1, float* __restrict__ bias2) {
    int idx = blockIdx.x * 256 + threadIdx.x;
    const int total = NHEAD * ANUM * NTOK;
    if (idx >= total) return;
    int h = idx / (ANUM * NTOK);
    int r = idx % (ANUM * NTOK);
    int a = r / NTOK;
    int n = r % NTOK;
    float v1, v2;
    if (n == 0) {
        v1 = ac[h * ANUM + a];
        v2 = ca[h * ANUM + a];
    } else {
        int p = n - 1, y = p / WIN, x = p % WIN;
        int haidx = h * ANUM + a;
        v1 = bilin7(an + haidx * 49, y, x) + ah[haidx * WIN + y] + aw[haidx * WIN + x];
        v2 = bilin7(na + haidx * 49, y, x) + ha[(h * WIN + y) * ANUM + a] + wa[(h * WIN + x) * ANUM + a];
    }
    bias1[(h * ANUM + a) * NTOK + n] = v1;
    bias2[((size_t)h * NTOK + n) * ANUM + a] = v2;
}

// ---------------- MFMA qkv GEMM: C = X16 @ W16^T, scatter f16 store --------
// A: (M,768) f16, B: (2304,768) f16. 128x128 tile, BK=32, 2x2 waves of 64x64.
// Linear grid (7074 blocks) with bijective XCD-chunk swizzle: each XCD walks
// contiguous m-tiles across all 18 n-tiles (A streams once, B L2-resident).
// Double-buffered LDS: next K-step's global_load_lds issued before current
// tile's MFMAs; one barrier per K-step.
__global__ __launch_bounds__(256) void mfma_qkv(const f16* __restrict__ A,
                                                const f16* __restrict__ B,
                                                f16* __restrict__ qo,
                                                f16* __restrict__ ko,
                                                f16* __restrict__ vo,
                                                f16* __restrict__ vto) {
    __shared__ f16 As[2][128 * 32];
    __shared__ f16 Bs[2][128 * 32];
    const int K = CDIM;
    int tid = threadIdx.x, wave = tid >> 6, lane = tid & 63;
    int quad = lane >> 4, col = lane & 15;

    // nwg = 393*18 = 7074 = 8*884 + 2 -> q=884, r=2 (m204 bijective swizzle)
    int bid = blockIdx.x;
    int xcd = bid & 7, sidx = bid >> 3;
    int wg = (xcd < 2 ? xcd * 885 : 2 * 885 + (xcd - 2) * 884) + sidx;
    int m0 = (wg / 18) * 128, n0 = (wg % 18) * 128;
    int wm = wave >> 1, wn = wave & 1;

    int srow = wave * 16 + (lane >> 2);
    int skc  = (lane & 3) * 8;
    int ar0 = min(m0 + srow, MROWS - 1);
    int ar1 = min(m0 + srow + 64, MROWS - 1);
    const f16* agp0 = A + (size_t)ar0 * K + skc;
    const f16* agp1 = A + (size_t)ar1 * K + skc;
    const f16* bgp0 = B + (size_t)(n0 + srow) * K + skc;
    const f16* bgp1 = B + (size_t)(n0 + srow + 64) * K + skc;

    f32x4 acc[4][4];
#pragma unroll
    for (int i = 0; i < 4; ++i)
#pragma unroll
        for (int j = 0; j < 4; ++j) acc[i][j] = (f32x4){0.f, 0.f, 0.f, 0.f};

    // prologue: stage k0=0 into buffer 0
    GLL(agp0, &As[0][wave * 512]);
    GLL(agp1, &As[0][2048 + wave * 512]);
    GLL(bgp0, &Bs[0][wave * 512]);
    GLL(bgp1, &Bs[0][2048 + wave * 512]);
    __syncthreads();

    int cur = 0;
    for (int k0 = 0; k0 < K; k0 += 32) {
        int nxt = cur ^ 1;
        if (k0 + 32 < K) {
            GLL(agp0 + k0 + 32, &As[nxt][wave * 512]);
            GLL(agp1 + k0 + 32, &As[nxt][2048 + wave * 512]);
            GLL(bgp0 + k0 + 32, &Bs[nxt][wave * 512]);
            GLL(bgp1 + k0 + 32, &Bs[nxt][2048 + wave * 512]);
        }
        f16x8 af[4], bf[4];
#pragma unroll
        for (int mt = 0; mt < 4; ++mt)
            af[mt] = *(const f16x8*)&As[cur][(wm * 64 + mt * 16 + col) * 32 + quad * 8];
#pragma unroll
        for (int nt = 0; nt < 4; ++nt)
            bf[nt] = *(const f16x8*)&Bs[cur][(wn * 64 + nt * 16 + col) * 32 + quad * 8];
#pragma unroll
        for (int mt = 0; mt < 4; ++mt)
#pragma unroll
            for (int nt = 0; nt < 4; ++nt)
                acc[mt][nt] = __builtin_amdgcn_mfma_f32_16x16x32_f16(af[mt], bf[nt], acc[mt][nt], 0, 0, 0);
        __syncthreads();   // drains prefetch vmcnt + guards LDS reuse
        cur = nxt;
    }

    int nbase = n0 + wn * 64;
    int t = nbase / CDIM;
    int h = (nbase % CDIM) >> 6;
    f16* Ob = (t == 0) ? qo : (t == 1) ? ko : vo;
#pragma unroll
    for (int mt = 0; mt < 4; ++mt) {
#pragma unroll
        for (int r = 0; r < 4; ++r) {
            int m = m0 + wm * 64 + mt * 16 + quad * 4 + r;
            if (m < MROWS) {
                int bb = m / NTOK, nn = m - bb * NTOK;
                size_t obase = (((size_t)bb * NHEAD + h) * NTOK + nn) * HDIM;
#pragma unroll
                for (int nt = 0; nt < 4; ++nt) {
                    f16 v = (f16)acc[mt][nt][r];
                    Ob[obase + nt * 16 + col] = v;
                    if (t == 2)
                        vto[(((size_t)bb * NHEAD + h) * HDIM + nt * 16 + col) * 800 + nn] = v;
                }
            }
        }
    }
}

// ---------------- MFMA proj GEMM: D = Y16 @ WP16^T + bias (fp32 out) -------
// Same structure as mfma_qkv: linear grid 393*6 = 2358 = 8*294 + 6.
__global__ __launch_bounds__(256) void mfma_proj(const f16* __restrict__ A,
                                                 const f16* __restrict__ B,
                                                 const float* __restrict__ bias,
                                                 float* __restrict__ D) {
    __shared__ f16 As[2][128 * 32];
    __shared__ f16 Bs[2][128 * 32];
    const int K = CDIM;
    int tid = threadIdx.x, wave = tid >> 6, lane = tid & 63;
    int quad = lane >> 4, col = lane & 15;

    // nwg = 2358 -> q=294, r=6
    int bid = blockIdx.x;
    int xcd = bid & 7, sidx = bid >> 3;
    int wg = (xcd < 6 ? xcd * 295 : 6 * 295 + (xcd - 6) * 294) + sidx;
    int m0 = (wg / 6) * 128, n0 = (wg % 6) * 128;
    int wm = wave >> 1, wn = wave & 1;

    int srow = wave * 16 + (lane >> 2);
    int skc  = (lane & 3) * 8;
    int ar0 = min(m0 + srow, MROWS - 1);
    int ar1 = min(m0 + srow + 64, MROWS - 1);
    const f16* agp0 = A + (size_t)ar0 * K + skc;
    const f16* agp1 = A + (size_t)ar1 * K + skc;
    const f16* bgp0 = B + (size_t)(n0 + srow) * K + skc;
    const f16* bgp1 = B + (size_t)(n0 + srow + 64) * K + skc;

    f32x4 acc[4][4];
#pragma unroll
    for (int i = 0; i < 4; ++i)
#pragma unroll
        for (int j = 0; j < 4; ++j) acc[i][j] = (f32x4){0.f, 0.f, 0.f, 0.f};

    GLL(agp0, &As[0][wave * 512]);
    GLL(agp1, &As[0][2048 + wave * 512]);
    GLL(bgp0, &Bs[0][wave * 512]);
    GLL(bgp1, &Bs[0][2048 + wave * 512]);
    __syncthreads();

    int cur = 0;
    for (int k0 = 0; k0 < K; k0 += 32) {
        int nxt = cur ^ 1;
        if (k0 + 32 < K) {
            GLL(agp0 + k0 + 32, &As[nxt][wave * 512]);
            GLL(agp1 + k0 + 32, &As[nxt][2048 + wave * 512]);
            GLL(bgp0 + k0 + 32, &Bs[nxt][wave * 512]);
            GLL(bgp1 + k0 + 32, &Bs[nxt][2048 + wave * 512]);
        }
        f16x8 af[4], bf[4];
#pragma unroll
        for (int mt = 0; mt < 4; ++mt)
            af[mt] = *(const f16x8*)&As[cur][(wm * 64 + mt * 16 + col) * 32 + quad * 8];
#pragma unroll
        for (int nt = 0; nt < 4; ++nt)
            bf[nt] = *(const f16x8*)&Bs[cur][(wn * 64 + nt * 16 + col) * 32 + quad * 8];
#pragma unroll
        for (int mt = 0; mt < 4; ++mt)
#pragma unroll
            for (int nt = 0; nt < 4; ++nt)
                acc[mt][nt] = __builtin_amdgcn_mfma_f32_16x16x32_f16(af[mt], bf[nt], acc[mt][nt], 0, 0, 0);
        __syncthreads();
        cur = nxt;
    }

    int nb = n0 + wn * 64;
    float bv[4];
#pragma unroll
    for (int nt = 0; nt < 4; ++nt) bv[nt] = bias[nb + nt * 16 + col];
#pragma unroll
    for (int mt = 0; mt < 4; ++mt) {
#pragma unroll
        for (int r = 0; r < 4; ++r) {
            int m = m0 + wm * 64 + mt * 16 + quad * 4 + r;
            if (m < MROWS) {
                float* dp = D + (size_t)m * CDIM + nb;
#pragma unroll
                for (int nt = 0; nt < 4; ++nt)
                    dp[nt * 16 + col] = acc[mt][nt][r] + bv[nt];
            }
        }
    }
}

// ---------------- agent pooling -> agent16 (f16, pre-scaled by 0.125) ------
__global__ void pool_kernel(const f16* __restrict__ q16, f16* __restrict__ agent16) {
    int bidx = blockIdx.x;           // (b, h, a)
    int d = threadIdx.x;             // 64 threads
    int b = bidx / (NHEAD * ANUM);
    int r = bidx % (NHEAD * ANUM);
    int h = r / ANUM;
    int a = r % ANUM;
    int py = a / 7, px = a % 7;
    const f16* base = q16 + ((size_t)(b * NHEAD + h) * NTOK) * HDIM;
    float s = 0.f;
#pragma unroll
    for (int dy = 0; dy < 4; ++dy)
#pragma unroll
        for (int dx = 0; dx < 4; ++dx) {
            int n = 1 + (py * 4 + dy) * WIN + (px * 4 + dx);
            s += (float)base[(size_t)n * HDIM + d];
        }
    agent16[((size_t)(b * NHEAD + h) * 64 + a) * 64 + d] = (f16)(s * (1.0f / 16.0f) * 0.125f);
}

// ---------------- stage1 scores: S1 = agent16 . K^T + bias1 -> P (f16) -----
__global__ __launch_bounds__(256) void s1_score(const f16* __restrict__ k16,
                                                const f16* __restrict__ agent16,
                                                const float* __restrict__ bias1,
                                                f16* __restrict__ P) {
    int bh = blockIdx.x;
    int h = bh % NHEAD;
    int wid = threadIdx.x >> 6;
    int lane = threadIdx.x & 63;
    int quad = lane >> 4, col = lane & 15;
    const f16* ag = agent16 + (size_t)bh * 4096;
    f16x8 afr[4][2];
#pragma unroll
    for (int mt = 0; mt < 4; ++mt)
#pragma unroll
        for (int ks = 0; ks < 2; ++ks)
            afr[mt][ks] = *(const f16x8*)(ag + (mt * 16 + col) * 64 + ks * 32 + quad * 8);
    const f16* kb = k16 + (size_t)bh * (NTOK * HDIM);
    f16* Pb = P + (size_t)bh * (64 * 800);
    for (int nt = wid; nt < 50; nt += 4) {
        int nn = nt * 16 + col;
        f16x8 b0 = *(const f16x8*)(kb + (size_t)nn * 64 + quad * 8);
        f16x8 b1 = *(const f16x8*)(kb + (size_t)nn * 64 + 32 + quad * 8);
#pragma unroll
        for (int mt = 0; mt < 4; ++mt) {
            f32x4 c = {0.f, 0.f, 0.f, 0.f};
            c = __builtin_amdgcn_mfma_f32_16x16x32_f16(afr[mt][0], b0, c, 0, 0, 0);
            c = __builtin_amdgcn_mfma_f32_16x16x32_f16(afr[mt][1], b1, c, 0, 0, 0);
#pragma unroll
            for (int r = 0; r < 4; ++r) {
                int a = mt * 16 + quad * 4 + r;
                float v = c[r];
                if (a < ANUM && nn < NTOK) v += bias1[(h * ANUM + a) * NTOK + nn];
                Pb[(size_t)a * 800 + nn] = (f16)v;
            }
        }
    }
}

// ---------------- generic in-place row softmax over f16 buffer -------------
__global__ __launch_bounds__(256) void softmax16(f16* __restrict__ buf, int total_rows,
                                                 int rpb_valid, int rpb_alloc,
                                                 int valid, int stride) {
    int wid = threadIdx.x >> 6, lane = threadIdx.x & 63;
    int r = blockIdx.x * 4 + wid;
    if (r >= total_rows) return;
    int bh = r / rpb_valid, i0 = r % rpb_valid;
    f16* p = buf + ((size_t)bh * rpb_alloc + i0) * stride;
    float m = -1e30f;
    for (int i = lane; i < valid; i += 64) m = fmaxf(m, (float)p[i]);
#pragma unroll
    for (int off = 32; off > 0; off >>= 1) m = fmaxf(m, __shfl_xor(m, off));
    float s = 0.f;
    for (int i = lane; i < valid; i += 64) s += __expf((float)p[i] - m);
#pragma unroll
    for (int off = 32; off > 0; off >>= 1) s += __shfl_xor(s, off);
    float inv = 1.0f / s;
    for (int i = lane; i < stride; i += 64) {
        float v = (i < valid) ? __expf((float)p[i] - m) * inv : 0.f;
        p[i] = (f16)v;
    }
}

// ---------------- stage1 PV: agentv^T = (P1 . V)^T ------------------------
__global__ __launch_bounds__(256) void s1_pv(const f16* __restrict__ P,
                                             const f16* __restrict__ vT,
                                             f16* __restrict__ avT) {
    int bh = blockIdx.x;
    int wid = threadIdx.x >> 6;
    int lane = threadIdx.x & 63;
    int quad = lane >> 4, col = lane & 15;
    const f16* Pb = P + (size_t)bh * 51200;
    const f16* Vt = vT + (size_t)bh * 51200;
    int m0 = wid * 16;
    f32x4 acc0 = {0.f, 0.f, 0.f, 0.f}, acc1 = acc0, acc2 = acc0, acc3 = acc0;
    for (int ks = 0; ks < 25; ++ks) {
        int k0 = ks * 32 + quad * 8;
        f16x8 a  = *(const f16x8*)(Pb + (size_t)(m0 + col) * 800 + k0);
        f16x8 b0 = *(const f16x8*)(Vt + (size_t)(col) * 800 + k0);
        f16x8 b1 = *(const f16x8*)(Vt + (size_t)(16 + col) * 800 + k0);
        f16x8 b2 = *(const f16x8*)(Vt + (size_t)(32 + col) * 800 + k0);
        f16x8 b3 = *(const f16x8*)(Vt + (size_t)(48 + col) * 800 + k0);
        acc0 = __builtin_amdgcn_mfma_f32_16x16x32_f16(a, b0, acc0, 0, 0, 0);
        acc1 = __builtin_amdgcn_mfma_f32_16x16x32_f16(a, b1, acc1, 0, 0, 0);
        acc2 = __builtin_amdgcn_mfma_f32_16x16x32_f16(a, b2, acc2, 0, 0, 0);
        acc3 = __builtin_amdgcn_mfma_f32_16x16x32_f16(a, b3, acc3, 0, 0, 0);
    }
    f16* av = avT + (size_t)bh * 4096;
#pragma unroll
    for (int dt = 0; dt < 4; ++dt) {
        f32x4 acc = (dt == 0) ? acc0 : (dt == 1) ? acc1 : (dt == 2) ? acc2 : acc3;
        f16x4 o;
#pragma unroll
        for (int r = 0; r < 4; ++r) o[r] = (f16)acc[r];
        *(f16x4*)(av + (size_t)(dt * 16 + col) * 64 + m0 + quad * 4) = o;
    }
}

// ---------------- stage2 scores: S2 = q . agent16^T + bias2 -> P (f16) -----
__global__ __launch_bounds__(256) void s2_score(const f16* __restrict__ q16,
                                                const f16* __restrict__ agent16,
                                                const float* __restrict__ bias2,
                                                f16* __restrict__ P) {
    int bh = blockIdx.x;
    int h = bh % NHEAD;
    int wid = threadIdx.x >> 6, lane = threadIdx.x & 63;
    int quad = lane >> 4, col = lane & 15;
    int qt = blockIdx.y * 4 + wid;
    if (qt >= 50) return;
    int n0 = qt * 16;
    const f16* qb = q16 + (size_t)bh * (NTOK * HDIM);
    f16x8 a0 = *(const f16x8*)(qb + (size_t)(n0 + col) * 64 + quad * 8);
    f16x8 a1 = *(const f16x8*)(qb + (size_t)(n0 + col) * 64 + 32 + quad * 8);
    const f16* ag = agent16 + (size_t)bh * 4096;
    f16* Pb = P + (size_t)bh * 51200;
#pragma unroll
    for (int at = 0; at < 4; ++at) {
        f16x8 b0 = *(const f16x8*)(ag + (at * 16 + col) * 64 + quad * 8);
        f16x8 b1 = *(const f16x8*)(ag + (at * 16 + col) * 64 + 32 + quad * 8);
        f32x4 c = {0.f, 0.f, 0.f, 0.f};
        c = __builtin_amdgcn_mfma_f32_16x16x32_f16(a0, b0, c, 0, 0, 0);
        c = __builtin_amdgcn_mfma_f32_16x16x32_f16(a1, b1, c, 0, 0, 0);
#pragma unroll
        for (int r = 0; r < 4; ++r) {
            int n = n0 + quad * 4 + r;
            int aa = at * 16 + col;
            float v = c[r];
            if (n < NTOK && aa < ANUM) v += bias2[((size_t)h * NTOK + n) * ANUM + aa];
            Pb[(size_t)n * 64 + aa] = (f16)v;
        }
    }
}

// ---------------- stage2 out: y = P2 . agentv -----------------------------
__global__ __launch_bounds__(256) void s2_out(const f16* __restrict__ P,
                                              const f16* __restrict__ avT,
                                              f16* __restrict__ y16) {
    int bh = blockIdx.x;
    int b = bh / NHEAD, h = bh % NHEAD;
    int wid = threadIdx.x >> 6, lane = threadIdx.x & 63;
    int quad = lane >> 4, col = lane & 15;
    int qt = blockIdx.y * 4 + wid;
    if (qt >= 50) return;
    int n0 = qt * 16;
    const f16* Pb = P + (size_t)bh * 51200;
    f16x8 a0 = *(const f16x8*)(Pb + (size_t)(n0 + col) * 64 + quad * 8);
    f16x8 a1 = *(const f16x8*)(Pb + (size_t)(n0 + col) * 64 + 32 + quad * 8);
    const f16* av = avT + (size_t)bh * 4096;
#pragma unroll
    for (int dt = 0; dt < 4; ++dt) {
        f16x8 b0 = *(const f16x8*)(av + (dt * 16 + col) * 64 + quad * 8);
        f16x8 b1 = *(const f16x8*)(av + (dt * 16 + col) * 64 + 32 + quad * 8);
        f32x4 c = {0.f, 0.f, 0.f, 0.f};
        c = __builtin_amdgcn_mfma_f32_16x16x32_f16(a0, b0, c, 0, 0, 0);
        c = __builtin_amdgcn_mfma_f32_16x16x32_f16(a1, b1, c, 0, 0, 0);
#pragma unroll
        for (int r = 0; r < 4; ++r) {
            int n = n0 + quad * 4 + r;
            if (n < NTOK)
                y16[((size_t)b * NTOK + n) * CDIM + h * HDIM + dt * 16 + col] = (f16)c[r];
        }
    }
}

// ---------------- depthwise 3x3 conv on V image tokens, add into y ---------
__global__ void dwc_kernel(const f16* __restrict__ v16, const float* __restrict__ w,
                           const float* __restrict__ bias, f16* __restrict__ y16) {
    int c = blockIdx.x * 256 + threadIdx.x;  // 0..767
    int p = blockIdx.y;                      // 0..783
    int b = blockIdx.z;                      // 0..63
    int h = c >> 6, d = c & 63;
    int y = p / WIN, x = p % WIN;
    const f16* vb = v16 + ((size_t)(b * NHEAD + h) * NTOK) * HDIM + d;
    float acc = bias[c];
#pragma unroll
    for (int ky = 0; ky < 3; ++ky) {
        int yy = y + ky - 1;
        if (yy < 0 || yy >= WIN) continue;
#pragma unroll
        for (int kx = 0; kx < 3; ++kx) {
            int xx = x + kx - 1;
            if (xx < 0 || xx >= WIN) continue;
            int nn = 1 + yy * WIN + xx;
            acc += (float)vb[(size_t)nn * HDIM] * w[(ky * 3 + kx) * CDIM + c];
        }
    }
    size_t yi = ((size_t)b * NTOK + 1 + p) * CDIM + c;
    y16[yi] = (f16)((float)y16[yi] + acc);
}

// ---------------- launch ---------------------------------------------------
extern "C" void kernel_launch(void* const* d_in, const int* in_sizes, int n_in,
                              void* d_out, int out_size, void* d_ws, size_t ws_size,
                              hipStream_t stream) {
    const float* x      = (const float*)d_in[0];
    const float* w_qkv  = (const float*)d_in[1];
    const float* w_proj = (const float*)d_in[2];
    const float* b_proj = (const float*)d_in[3];
    const float* dwc_w  = (const float*)d_in[4];
    const float* dwc_b  = (const float*)d_in[5];
    const float* an     = (const float*)d_in[6];
    const float* ah     = (const float*)d_in[7];
    const float* aw     = (const float*)d_in[8];
    const float* na     = (const float*)d_in[9];
    const float* ha     = (const float*)d_in[10];
    const float* wa     = (const float*)d_in[11];
    const float* ac     = (const float*)d_in[12];
    const float* ca     = (const float*)d_in[13];
    float* out = (float*)d_out;

    char* ws = (char*)d_ws;
    f16* q16   = (f16*)(ws + OFF_Q);
    f16* k16   = (f16*)(ws + OFF_K);
    f16* v16   = (f16*)(ws + OFF_V);
    f16* y16   = (f16*)(ws + OFF_Y);
    f16* vT    = (f16*)(ws + OFF_VT);
    f16* Pbuf  = (f16*)(ws + OFF_P);
    f16* agent16 = (f16*)(ws + OFF_AG);
    f16* avT   = (f16*)(ws + OFF_AVT);
    float* bias1 = (float*)(ws + OFF_B1);
    float* bias2 = (float*)(ws + OFF_B2);
    // overlays (lifetime-disjoint)
    f16* X16  = (f16*)(ws + OFF_P);    // x in fp16, consumed by mfma_qkv before P is written
    f16* W16  = (f16*)(ws + OFF_AVT);  // w_qkv fp16, consumed before avT is written
    f16* WP16 = (f16*)(ws + OFF_P);    // w_proj fp16, written after P fully consumed

    bias_kernel<<<(NHEAD * ANUM * NTOK + 255) / 256, 256, 0, stream>>>(
        an, ah, aw, ac, na, ha, wa, ca, bias1, bias2);

    // fp32 -> fp16 conversions
    cvt_kernel<<<(MROWS * CDIM / 4 + 255) / 256, 256, 0, stream>>>(x, X16, MROWS * CDIM / 4);
    cvt_kernel<<<(3 * CDIM * CDIM / 4 + 255) / 256, 256, 0, stream>>>(w_qkv, W16, 3 * CDIM * CDIM / 4);

    // qkv GEMM (MFMA) -> q16/k16/v16 (head-major) + vT
    // linear grid: 393 m-tiles * 18 n-tiles = 7074 blocks (swizzled in-kernel)
    mfma_qkv<<<7074, 256, 0, stream>>>(X16, W16, q16, k16, v16, vT);

    pool_kernel<<<BATCH * NHEAD * ANUM, 64, 0, stream>>>(q16, agent16);

    // stage 1: scores -> softmax (in place) -> PV
    s1_score<<<BATCH * NHEAD, 256, 0, stream>>>(k16, agent16, bias1, Pbuf);
    softmax16<<<(BATCH * NHEAD * ANUM + 3) / 4, 256, 0, stream>>>(
        Pbuf, BATCH * NHEAD * ANUM, ANUM, 64, NTOK, 800);
    s1_pv<<<BATCH * NHEAD, 256, 0, stream>>>(Pbuf, vT, avT);

    // stage 2: scores -> softmax (in place) -> out (reuses Pbuf)
    s2_score<<<dim3(BATCH * NHEAD, 13), 256, 0, stream>>>(q16, agent16, bias2, Pbuf);
    softmax16<<<(BATCH * NHEAD * NTOK + 3) / 4, 256, 0, stream>>>(
        Pbuf, BATCH * NHEAD * NTOK, NTOK, 800, ANUM, 64);
    s2_out<<<dim3(BATCH * NHEAD, 13), 256, 0, stream>>>(Pbuf, avT, y16);

    dwc_kernel<<<dim3(CDIM / 256, WIN * WIN, BATCH), 256, 0, stream>>>(v16, dwc_w, dwc_b, y16);

    // output projection (MFMA)
    cvt_kernel<<<(CDIM * CDIM / 4 + 255) / 256, 256, 0, stream>>>(w_proj, WP16, CDIM * CDIM / 4);
    // linear grid: 393 m-tiles * 6 n-tiles = 2358 blocks (swizzled in-kernel)
    mfma_proj<<<2358, 256, 0, stream>>>(y16, WP16, b_proj, out);
}

// Round 3
// 1432.930 us; speedup vs baseline: 1.0390x; 1.0294x over previous
//
#include <hip/hip_runtime.h>
#include <hip/hip_fp16.h>

typedef _Float16 f16;
typedef _Float16 f16x8 __attribute__((ext_vector_type(8)));
typedef _Float16 f16x4 __attribute__((ext_vector_type(4)));
typedef float f32x4 __attribute__((ext_vector_type(4)));

// Problem constants
#define BATCH 64
#define NTOK 785          // 1 + 28*28
#define CDIM 768
#define NHEAD 12
#define HDIM 64
#define ANUM 49
#define WIN 28
#define MROWS (BATCH * NTOK)   // 50240

// ---------------- workspace layout (bytes) ----------------
#define SZ_Q   77168640ULL                 // (B*H*N*64) halves
#define OFF_Q  0ULL
#define OFF_K  (OFF_Q + SZ_Q)
#define OFF_V  (OFF_K + SZ_Q)
#define OFF_Y  (OFF_V + SZ_Q)
#define OFF_VT (OFF_Y + SZ_Q)              // V transposed: (bh, d=64, n=800) f16
#define SZ_VT  78643200ULL
#define OFF_P  (OFF_VT + SZ_VT)            // P1 (bh,64,800) / P2 (bh,800,64) f16; also X16 / WP16 overlay
#define SZ_P   78643200ULL
#define OFF_AG (OFF_P + SZ_P)              // agent16: (bh, 64, 64) f16, scaled by 0.125
#define SZ_AG  6291456ULL
#define OFF_AVT (OFF_AG + SZ_AG)           // agentv^T: (bh, d=64, a=64) f16; also W16 overlay
#define OFF_B1 (OFF_AVT + SZ_AG)
#define SZ_B   1846320ULL
#define OFF_B2 (OFF_B1 + SZ_B)

#define GLL(g, l) __builtin_amdgcn_global_load_lds( \
    (const __attribute__((address_space(1))) void*)(g), \
    (__attribute__((address_space(3))) void*)(l), 16, 0, 0)

#define BAR()  asm volatile("s_barrier" ::: "memory")
#define VMW2() asm volatile("s_waitcnt vmcnt(2)" ::: "memory")
#define VMW0() asm volatile("s_waitcnt vmcnt(0)" ::: "memory")

// ---------------- fp32 -> fp16 conversion (x4 vectorized) -------------------
__global__ void cvt_kernel(const float* __restrict__ s, f16* __restrict__ d, int n4) {
    int i = blockIdx.x * 256 + threadIdx.x;
    if (i >= n4) return;
    float4 v = ((const float4*)s)[i];
    f16x4 o = {(f16)v.x, (f16)v.y, (f16)v.z, (f16)v.w};
    ((f16x4*)d)[i] = o;
}

// ---------------- bilinear (jax.image.resize, half-pixel centers, 7->28) ----
__device__ __forceinline__ float bilin7(const float* __restrict__ t, int y, int x) {
    float fy = 0.25f * (float)y - 0.375f;
    float fx = 0.25f * (float)x - 0.375f;
    int y0 = (int)floorf(fy);
    int x0 = (int)floorf(fx);
    float wy = fy - (float)y0, wx = fx - (float)x0;
    int y0c = max(0, min(6, y0)),     y1c = max(0, min(6, y0 + 1));
    int x0c = max(0, min(6, x0)),     x1c = max(0, min(6, x0 + 1));
    float v00 = t[y0c * 7 + x0c], v01 = t[y0c * 7 + x1c];
    float v10 = t[y1c * 7 + x0c], v11 = t[y1c * 7 + x1c];
    return (1.f - wy) * ((1.f - wx) * v00 + wx * v01) +
           wy        * ((1.f - wx) * v10 + wx * v11);
}

// ---------------- bias kernel: builds bias1[h][a][n] and bias2[h][n][a] -----
__global__ void bias_kernel(const float* __restrict__ an, const float* __restrict__ ah,
                            const float* __restrict__ aw, const float* __restrict__ ac,
                            const float* __restrict__ na, const float* __restrict__ ha,
                            const float* __restrict__ wa, const float* __restrict__ ca,
                            float* __restrict__ bias1, float* __restrict__ bias2) {
    int idx = blockIdx.x * 256 + threadIdx.x;
    const int total = NHEAD * ANUM * NTOK;
    if (idx >= total) return;
    int h = idx / (ANUM * NTOK);
    int r = idx % (ANUM * NTOK);
    int a = r / NTOK;
    int n = r % NTOK;
    float v1, v2;
    if (n == 0) {
        v1 = ac[h * ANUM + a];
        v2 = ca[h * ANUM + a];
    } else {
        int p = n - 1, y = p / WIN, x = p % WIN;
        int haidx = h * ANUM + a;
        v1 = bilin7(an + haidx * 49, y, x) + ah[haidx * WIN + y] + aw[haidx * WIN + x];
        v2 = bilin7(na + haidx * 49, y, x) + ha[(h * WIN + y) * ANUM + a] + wa[(h * WIN + x) * ANUM + a];
    }
    bias1[(h * ANUM + a) * NTOK + n] = v1;
    bias2[((size_t)h * NTOK + n) * ANUM + a] = v2;
}

// ============================================================================
// 256x256 8-phase MFMA GEMM core (T2+T3+T4+T5 port).
// 512 threads = 8 waves (2 wm x 4 wn), each wave owns 128x64 output.
// BK=64, 12 K-tiles, double-buffered 128KB LDS, counted vmcnt (never 0 in
// steady state), granule-XOR swizzle: LDS slot s of row r holds global
// granule s^(r&7) (both-sides: pre-swizzled global source for linear-dest
// global_load_lds + same XOR on ds_read) -> conflict-free ds_read_b128.
// LDS (f16 units): buffer p at p*32768; A rows [0,256)x64, B at +16384.
// ============================================================================
__device__ __forceinline__ void gemm_core_256(const f16* __restrict__ Ag,
                                              const f16* __restrict__ Bg,
                                              int m0, int n0, f16* sm,
                                              f32x4 (&acc)[8][4]) {
    const int tid = threadIdx.x, w = tid >> 6, l = tid & 63;
    const int c = l & 15, q = l >> 4;
    const int wm = w >> 2, wn = w & 3;
    const int rl = l >> 3;                    // source row within 8-row unit
    const int gl = (l & 7) ^ (rl & 7);        // source granule for linear dest
    const f16* pA[4];
    const f16* pB[4];
#pragma unroll
    for (int j = 0; j < 4; ++j) {
        int ra = m0 + w * 32 + j * 8 + rl;
        ra = min(ra, MROWS - 1);
        pA[j] = Ag + (size_t)ra * CDIM + gl * 8;
        pB[j] = Bg + (size_t)(n0 + w * 32 + j * 8 + rl) * CDIM + gl * 8;
    }
    const int gx0 = (q ^ (c & 7)) * 8;        // kk=0 granule slot
    const int gx1 = ((4 + q) ^ (c & 7)) * 8;  // kk=1
    const int laneA = (wm * 128 + c) * 64;
    const int laneB = 16384 + (wn * 64 + c) * 64;

#pragma unroll
    for (int i = 0; i < 8; ++i)
#pragma unroll
        for (int j = 0; j < 4; ++j) acc[i][j] = (f32x4){0.f, 0.f, 0.f, 0.f};

    auto stagej = [&](int kt, int j) {
        int bb = (kt & 1) ? 32768 : 0;
        GLL(pA[j] + (size_t)kt * 64, sm + bb + w * 2048 + j * 512);
        GLL(pB[j] + (size_t)kt * 64, sm + bb + 16384 + w * 2048 + j * 512);
    };

#pragma unroll
    for (int j = 0; j < 4; ++j) stagej(0, j);

    for (int t = 0; t < 12; ++t) {
        const int sb = (t & 1) ? 32768 : 0;
        if (t < 11) { stagej(t + 1, 0); VMW2(); } else { VMW0(); }
        BAR();
        f16x8 af[4][2], bf[2][2];
#pragma unroll
        for (int ph = 0; ph < 4; ++ph) {
            const int mq = ph >> 1;
            const int nq = (ph == 1 || ph == 2) ? 1 : 0;
            if (ph == 0 || ph == 2) {
#pragma unroll
                for (int mf = 0; mf < 4; ++mf) {
                    int base = sb + laneA + (mq * 64 + mf * 16) * 64;
                    af[mf][0] = *(const f16x8*)(sm + base + gx0);
                    af[mf][1] = *(const f16x8*)(sm + base + gx1);
                }
            }
            if (ph != 2) {
#pragma unroll
                for (int jf = 0; jf < 2; ++jf) {
                    int base = sb + laneB + (nq * 32 + jf * 16) * 64;
                    bf[jf][0] = *(const f16x8*)(sm + base + gx0);
                    bf[jf][1] = *(const f16x8*)(sm + base + gx1);
                }
            }
            if (t < 11 && ph < 3) stagej(t + 1, ph + 1);
            BAR();
            __builtin_amdgcn_s_setprio(1);
#pragma unroll
            for (int i = 0; i < 4; ++i)
#pragma unroll
                for (int jf = 0; jf < 2; ++jf) {
                    acc[mq * 4 + i][nq * 2 + jf] = __builtin_amdgcn_mfma_f32_16x16x32_f16(
                        af[i][0], bf[jf][0], acc[mq * 4 + i][nq * 2 + jf], 0, 0, 0);
                    acc[mq * 4 + i][nq * 2 + jf] = __builtin_amdgcn_mfma_f32_16x16x32_f16(
                        af[i][1], bf[jf][1], acc[mq * 4 + i][nq * 2 + jf], 0, 0, 0);
                }
            __builtin_amdgcn_s_setprio(0);
            __builtin_amdgcn_sched_barrier(0);
            BAR();
        }
    }
}

// ---------------- MFMA qkv GEMM: C = X16 @ W16^T, scatter f16 store --------
__global__ __launch_bounds__(512) void mfma_qkv(const f16* __restrict__ Ag,
                                                const f16* __restrict__ Bg,
                                                f16* __restrict__ qo,
                                                f16* __restrict__ ko,
                                                f16* __restrict__ vo,
                                                f16* __restrict__ vto) {
    __shared__ f16 sm[65536];  // 128 KB
    // nwg = 197*9 = 1773 = 8*221 + 5 (bijective XCD swizzle, m204)
    int bid = blockIdx.x;
    int xcd = bid & 7, sidx = bid >> 3;
    int wg = (xcd < 5 ? xcd * 222 : 5 * 222 + (xcd - 5) * 221) + sidx;
    int m0 = (wg / 9) * 256, n0 = (wg % 9) * 256;

    f32x4 acc[8][4];
    gemm_core_256(Ag, Bg, m0, n0, sm, acc);

    const int tid = threadIdx.x, w = tid >> 6, l = tid & 63;
    const int c = l & 15, q = l >> 4;
    const int wm = w >> 2, wn = w & 3;
    const int nb = n0 + wn * 64;          // 64-aligned -> single head slice
    const int tsel = nb / CDIM;
    const int h = (nb % CDIM) >> 6;
    f16* Ob = (tsel == 0) ? qo : (tsel == 1) ? ko : vo;
#pragma unroll
    for (int mf = 0; mf < 8; ++mf) {
#pragma unroll
        for (int r = 0; r < 4; ++r) {
            int m = m0 + wm * 128 + mf * 16 + q * 4 + r;
            if (m < MROWS) {
                int bb = m / NTOK;
                int nn = m - bb * NTOK;
                size_t ob = (((size_t)bb * NHEAD + h) * NTOK + nn) * HDIM;
#pragma unroll
                for (int nf = 0; nf < 4; ++nf) {
                    f16 v = (f16)acc[mf][nf][r];
                    Ob[ob + nf * 16 + c] = v;
                    if (tsel == 2)
                        vto[(((size_t)bb * NHEAD + h) * HDIM + nf * 16 + c) * 800 + nn] = v;
                }
            }
        }
    }
}

// ---------------- MFMA proj GEMM: D = Y16 @ WP16^T + bias (fp32 out) -------
__global__ __launch_bounds__(512) void mfma_proj(const f16* __restrict__ Ag,
                                                 const f16* __restrict__ Bg,
                                                 const float* __restrict__ bias,
                                                 float* __restrict__ D) {
    __shared__ f16 sm[65536];  // 128 KB
    // nwg = 197*3 = 591 = 8*73 + 7
    int bid = blockIdx.x;
    int xcd = bid & 7, sidx = bid >> 3;
    int wg = (xcd < 7 ? xcd * 74 : 7 * 74 + (xcd - 7) * 73) + sidx;
    int m0 = (wg / 3) * 256, n0 = (wg % 3) * 256;

    f32x4 acc[8][4];
    gemm_core_256(Ag, Bg, m0, n0, sm, acc);

    const int tid = threadIdx.x, w = tid >> 6, l = tid & 63;
    const int c = l & 15, q = l >> 4;
    const int wm = w >> 2, wn = w & 3;
    const int nb = n0 + wn * 64;
    float bv[4];
#pragma unroll
    for (int nf = 0; nf < 4; ++nf) bv[nf] = bias[nb + nf * 16 + c];
#pragma unroll
    for (int mf = 0; mf < 8; ++mf) {
#pragma unroll
        for (int r = 0; r < 4; ++r) {
            int m = m0 + wm * 128 + mf * 16 + q * 4 + r;
            if (m < MROWS) {
                float* dp = D + (size_t)m * CDIM + nb;
#pragma unroll
                for (int nf = 0; nf < 4; ++nf)
                    dp[nf * 16 + c] = acc[mf][nf][r] + bv[nf];
            }
        }
    }
}

// ---------------- agent pooling -> agent16 (f16, pre-scaled by 0.125) ------
__global__ void pool_kernel(const f16* __restrict__ q16, f16* __restrict__ agent16) {
    int bidx = blockIdx.x;           // (b, h, a)
    int d = threadIdx.x;             // 64 threads
    int b = bidx / (NHEAD * ANUM);
    int r = bidx % (NHEAD * ANUM);
    int h = r / ANUM;
    int a = r % ANUM;
    int py = a / 7, px = a % 7;
    const f16* base = q16 + ((size_t)(b * NHEAD + h) * NTOK) * HDIM;
    float s = 0.f;
#pragma unroll
    for (int dy = 0; dy < 4; ++dy)
#pragma unroll
        for (int dx = 0; dx < 4; ++dx) {
            int n = 1 + (py * 4 + dy) * WIN + (px * 4 + dx);
            s += (float)base[(size_t)n * HDIM + d];
        }
    agent16[((size_t)(b * NHEAD + h) * 64 + a) * 64 + d] = (f16)(s * (1.0f / 16.0f) * 0.125f);
}

// ---------------- stage1 scores: S1 = agent16 . K^T + bias1 -> P (f16) -----
__global__ __launch_bounds__(256) void s1_score(const f16* __restrict__ k16,
                                                const f16* __restrict__ agent16,
                                                const float* __restrict__ bias1,
                                                f16* __restrict__ P) {
    int bh = blockIdx.x;
    int h = bh % NHEAD;
    int wid = threadIdx.x >> 6;
    int lane = threadIdx.x & 63;
    int quad = lane >> 4, col = lane & 15;
    const f16* ag = agent16 + (size_t)bh * 4096;
    f16x8 afr[4][2];
#pragma unroll
    for (int mt = 0; mt < 4; ++mt)
#pragma unroll
        for (int ks = 0; ks < 2; ++ks)
            afr[mt][ks] = *(const f16x8*)(ag + (mt * 16 + col) * 64 + ks * 32 + quad * 8);
    const f16* kb = k16 + (size_t)bh * (NTOK * HDIM);
    f16* Pb = P + (size_t)bh * (64 * 800);
    for (int nt = wid; nt < 50; nt += 4) {
        int nn = nt * 16 + col;
        f16x8 b0 = *(const f16x8*)(kb + (size_t)nn * 64 + quad * 8);
        f16x8 b1 = *(const f16x8*)(kb + (size_t)nn * 64 + 32 + quad * 8);
#pragma unroll
        for (int mt = 0; mt < 4; ++mt) {
            f32x4 cc = {0.f, 0.f, 0.f, 0.f};
            cc = __builtin_amdgcn_mfma_f32_16x16x32_f16(afr[mt][0], b0, cc, 0, 0, 0);
            cc = __builtin_amdgcn_mfma_f32_16x16x32_f16(afr[mt][1], b1, cc, 0, 0, 0);
#pragma unroll
            for (int r = 0; r < 4; ++r) {
                int a = mt * 16 + quad * 4 + r;
                float v = cc[r];
                if (a < ANUM && nn < NTOK) v += bias1[(h * ANUM + a) * NTOK + nn];
                Pb[(size_t)a * 800 + nn] = (f16)v;
            }
        }
    }
}

// ---------------- generic in-place row softmax over f16 buffer -------------
__global__ __launch_bounds__(256) void softmax16(f16* __restrict__ buf, int total_rows,
                                                 int rpb_valid, int rpb_alloc,
                                                 int valid, int stride) {
    int wid = threadIdx.x >> 6, lane = threadIdx.x & 63;
    int r = blockIdx.x * 4 + wid;
    if (r >= total_rows) return;
    int bh = r / rpb_valid, i0 = r % rpb_valid;
    f16* p = buf + ((size_t)bh * rpb_alloc + i0) * stride;
    float m = -1e30f;
    for (int i = lane; i < valid; i += 64) m = fmaxf(m, (float)p[i]);
#pragma unroll
    for (int off = 32; off > 0; off >>= 1) m = fmaxf(m, __shfl_xor(m, off));
    float s = 0.f;
    for (int i = lane; i < valid; i += 64) s += __expf((float)p[i] - m);
#pragma unroll
    for (int off = 32; off > 0; off >>= 1) s += __shfl_xor(s, off);
    float inv = 1.0f / s;
    for (int i = lane; i < stride; i += 64) {
        float v = (i < valid) ? __expf((float)p[i] - m) * inv : 0.f;
        p[i] = (f16)v;
    }
}

// ---------------- stage1 PV: agentv^T = (P1 . V)^T ------------------------
__global__ __launch_bounds__(256) void s1_pv(const f16* __restrict__ P,
                                             const f16* __restrict__ vT,
                                             f16* __restrict__ avT) {
    int bh = blockIdx.x;
    int wid = threadIdx.x >> 6;
    int lane = threadIdx.x & 63;
    int quad = lane >> 4, col = lane & 15;
    const f16* Pb = P + (size_t)bh * 51200;
    const f16* Vt = vT + (size_t)bh * 51200;
    int m0 = wid * 16;
    f32x4 acc0 = {0.f, 0.f, 0.f, 0.f}, acc1 = acc0, acc2 = acc0, acc3 = acc0;
    for (int ks = 0; ks < 25; ++ks) {
        int k0 = ks * 32 + quad * 8;
        f16x8 a  = *(const f16x8*)(Pb + (size_t)(m0 + col) * 800 + k0);
        f16x8 b0 = *(const f16x8*)(Vt + (size_t)(col) * 800 + k0);
        f16x8 b1 = *(const f16x8*)(Vt + (size_t)(16 + col) * 800 + k0);
        f16x8 b2 = *(const f16x8*)(Vt + (size_t)(32 + col) * 800 + k0);
        f16x8 b3 = *(const f16x8*)(Vt + (size_t)(48 + col) * 800 + k0);
        acc0 = __builtin_amdgcn_mfma_f32_16x16x32_f16(a, b0, acc0, 0, 0, 0);
        acc1 = __builtin_amdgcn_mfma_f32_16x16x32_f16(a, b1, acc1, 0, 0, 0);
        acc2 = __builtin_amdgcn_mfma_f32_16x16x32_f16(a, b2, acc2, 0, 0, 0);
        acc3 = __builtin_amdgcn_mfma_f32_16x16x32_f16(a, b3, acc3, 0, 0, 0);
    }
    f16* av = avT + (size_t)bh * 4096;
#pragma unroll
    for (int dt = 0; dt < 4; ++dt) {
        f32x4 acc = (dt == 0) ? acc0 : (dt == 1) ? acc1 : (dt == 2) ? acc2 : acc3;
        f16x4 o;
#pragma unroll
        for (int r = 0; r < 4; ++r) o[r] = (f16)acc[r];
        *(f16x4*)(av + (size_t)(dt * 16 + col) * 64 + m0 + quad * 4) = o;
    }
}

// ---------------- stage2 scores: S2 = q . agent16^T + bias2 -> P (f16) -----
__global__ __launch_bounds__(256) void s2_score(const f16* __restrict__ q16,
                                                const f16* __restrict__ agent16,
                                                const float* __restrict__ bias2,
                                                f16* __restrict__ P) {
    int bh = blockIdx.x;
    int h = bh % NHEAD;
    int wid = threadIdx.x >> 6, lane = threadIdx.x & 63;
    int quad = lane >> 4, col = lane & 15;
    int qt = blockIdx.y * 4 + wid;
    if (qt >= 50) return;
    int n0 = qt * 16;
    const f16* qb = q16 + (size_t)bh * (NTOK * HDIM);
    f16x8 a0 = *(const f16x8*)(qb + (size_t)(n0 + col) * 64 + quad * 8);
    f16x8 a1 = *(const f16x8*)(qb + (size_t)(n0 + col) * 64 + 32 + quad * 8);
    const f16* ag = agent16 + (size_t)bh * 4096;
    f16* Pb = P + (size_t)bh * 51200;
#pragma unroll
    for (int at = 0; at < 4; ++at) {
        f16x8 b0 = *(const f16x8*)(ag + (at * 16 + col) * 64 + quad * 8);
        f16x8 b1 = *(const f16x8*)(ag + (at * 16 + col) * 64 + 32 + quad * 8);
        f32x4 cc = {0.f, 0.f, 0.f, 0.f};
        cc = __builtin_amdgcn_mfma_f32_16x16x32_f16(a0, b0, cc, 0, 0, 0);
        cc = __builtin_amdgcn_mfma_f32_16x16x32_f16(a1, b1, cc, 0, 0, 0);
#pragma unroll
        for (int r = 0; r < 4; ++r) {
            int n = n0 + quad * 4 + r;
            int aa = at * 16 + col;
            float v = cc[r];
            if (n < NTOK && aa < ANUM) v += bias2[((size_t)h * NTOK + n) * ANUM + aa];
            Pb[(size_t)n * 64 + aa] = (f16)v;
        }
    }
}

// ---------------- stage2 out: y = P2 . agentv -----------------------------
__global__ __launch_bounds__(256) void s2_out(const f16* __restrict__ P,
                                              const f16* __restrict__ avT,
                                              f16* __restrict__ y16) {
    int bh = blockIdx.x;
    int b = bh / NHEAD, h = bh % NHEAD;
    int wid = threadIdx.x >> 6, lane = threadIdx.x & 63;
    int quad = lane >> 4, col = lane & 15;
    int qt = blockIdx.y * 4 + wid;
    if (qt >= 50) return;
    int n0 = qt * 16;
    const f16* Pb = P + (size_t)bh * 51200;
    f16x8 a0 = *(const f16x8*)(Pb + (size_t)(n0 + col) * 64 + quad * 8);
    f16x8 a1 = *(const f16x8*)(Pb + (size_t)(n0 + col) * 64 + 32 + quad * 8);
    const f16* av = avT + (size_t)bh * 4096;
#pragma unroll
    for (int dt = 0; dt < 4; ++dt) {
        f16x8 b0 = *(const f16x8*)(av + (dt * 16 + col) * 64 + quad * 8);
        f16x8 b1 = *(const f16x8*)(av + (dt * 16 + col) * 64 + 32 + quad * 8);
        f32x4 cc = {0.f, 0.f, 0.f, 0.f};
        cc = __builtin_amdgcn_mfma_f32_16x16x32_f16(a0, b0, cc, 0, 0, 0);
        cc = __builtin_amdgcn_mfma_f32_16x16x32_f16(a1, b1, cc, 0, 0, 0);
#pragma unroll
        for (int r = 0; r < 4; ++r) {
            int n = n0 + quad * 4 + r;
            if (n < NTOK)
                y16[((size_t)b * NTOK + n) * CDIM + h * HDIM + dt * 16 + col] = (f16)cc[r];
        }
    }
}

// ---------------- depthwise 3x3 conv on V image tokens, add into y ---------
__global__ void dwc_kernel(const f16* __restrict__ v16, const float* __restrict__ w,
                           const float* __restrict__ bias, f16* __restrict__ y16) {
    int c = blockIdx.x * 256 + threadIdx.x;  // 0..767
    int p = blockIdx.y;                      // 0..783
    int b = blockIdx.z;                      // 0..63
    int h = c >> 6, d = c & 63;
    int y = p / WIN, x = p % WIN;
    const f16* vb = v16 + ((size_t)(b * NHEAD + h) * NTOK) * HDIM + d;
    float acc = bias[c];
#pragma unroll
    for (int ky = 0; ky < 3; ++ky) {
        int yy = y + ky - 1;
        if (yy < 0 || yy >= WIN) continue;
#pragma unroll
        for (int kx = 0; kx < 3; ++kx) {
            int xx = x + kx - 1;
            if (xx < 0 || xx >= WIN) continue;
            int nn = 1 + yy * WIN + xx;
            acc += (float)vb[(size_t)nn * HDIM] * w[(ky * 3 + kx) * CDIM + c];
        }
    }
    size_t yi = ((size_t)b * NTOK + 1 + p) * CDIM + c;
    y16[yi] = (f16)((float)y16[yi] + acc);
}

// ---------------- launch ---------------------------------------------------
extern "C" void kernel_launch(void* const* d_in, const int* in_sizes, int n_in,
                              void* d_out, int out_size, void* d_ws, size_t ws_size,
                              hipStream_t stream) {
    const float* x      = (const float*)d_in[0];
    const float* w_qkv  = (const float*)d_in[1];
    const float* w_proj = (const float*)d_in[2];
    const float* b_proj = (const float*)d_in[3];
    const float* dwc_w  = (const float*)d_in[4];
    const float* dwc_b  = (const float*)d_in[5];
    const float* an     = (const float*)d_in[6];
    const float* ah     = (const float*)d_in[7];
    const float* aw     = (const float*)d_in[8];
    const float* na     = (const float*)d_in[9];
    const float* ha     = (const float*)d_in[10];
    const float* wa     = (const float*)d_in[11];
    const float* ac     = (const float*)d_in[12];
    const float* ca     = (const float*)d_in[13];
    float* out = (float*)d_out;

    char* ws = (char*)d_ws;
    f16* q16   = (f16*)(ws + OFF_Q);
    f16* k16   = (f16*)(ws + OFF_K);
    f16* v16   = (f16*)(ws + OFF_V);
    f16* y16   = (f16*)(ws + OFF_Y);
    f16* vT    = (f16*)(ws + OFF_VT);
    f16* Pbuf  = (f16*)(ws + OFF_P);
    f16* agent16 = (f16*)(ws + OFF_AG);
    f16* avT   = (f16*)(ws + OFF_AVT);
    float* bias1 = (float*)(ws + OFF_B1);
    float* bias2 = (float*)(ws + OFF_B2);
    // overlays (lifetime-disjoint)
    f16* X16  = (f16*)(ws + OFF_P);    // x in fp16, consumed by mfma_qkv before P is written
    f16* W16  = (f16*)(ws + OFF_AVT);  // w_qkv fp16, consumed before avT is written
    f16* WP16 = (f16*)(ws + OFF_P);    // w_proj fp16, written after P fully consumed

    bias_kernel<<<(NHEAD * ANUM * NTOK + 255) / 256, 256, 0, stream>>>(
        an, ah, aw, ac, na, ha, wa, ca, bias1, bias2);

    // fp32 -> fp16 conversions
    cvt_kernel<<<(MROWS * CDIM / 4 + 255) / 256, 256, 0, stream>>>(x, X16, MROWS * CDIM / 4);
    cvt_kernel<<<(3 * CDIM * CDIM / 4 + 255) / 256, 256, 0, stream>>>(w_qkv, W16, 3 * CDIM * CDIM / 4);

    // qkv GEMM (MFMA, 256x256 8-phase) -> q16/k16/v16 (head-major) + vT
    mfma_qkv<<<1773, 512, 0, stream>>>(X16, W16, q16, k16, v16, vT);

    pool_kernel<<<BATCH * NHEAD * ANUM, 64, 0, stream>>>(q16, agent16);

    // stage 1: scores -> softmax (in place) -> PV
    s1_score<<<BATCH * NHEAD, 256, 0, stream>>>(k16, agent16, bias1, Pbuf);
    softmax16<<<(BATCH * NHEAD * ANUM + 3) / 4, 256, 0, stream>>>(
        Pbuf, BATCH * NHEAD * ANUM, ANUM, 64, NTOK, 800);
    s1_pv<<<BATCH * NHEAD, 256, 0, stream>>>(Pbuf, vT, avT);

    // stage 2: scores -> softmax (in place) -> out (reuses Pbuf)
    s2_score<<<dim3(BATCH * NHEAD, 13), 256, 0, stream>>>(q16, agent16, bias2, Pbuf);
    softmax16<<<(BATCH * NHEAD * NTOK + 3) / 4, 256, 0, stream>>>(
        Pbuf, BATCH * NHEAD * NTOK, NTOK, 800, ANUM, 64);
    s2_out<<<dim3(BATCH * NHEAD, 13), 256, 0, stream>>>(Pbuf, avT, y16);

    dwc_kernel<<<dim3(CDIM / 256, WIN * WIN, BATCH), 256, 0, stream>>>(v16, dwc_w, dwc_b, y16);

    // output projection (MFMA, 256x256 8-phase)
    cvt_kernel<<<(CDIM * CDIM / 4 + 255) / 256, 256, 0, stream>>>(w_proj, WP16, CDIM * CDIM / 4);
    mfma_proj<<<591, 512, 0, stream>>>(y16, WP16, b_proj, out);
}

// Round 4
// 1405.351 us; speedup vs baseline: 1.0594x; 1.0196x over previous
//
#include <hip/hip_runtime.h>
#include <hip/hip_fp16.h>

typedef _Float16 f16;
typedef _Float16 f16x8 __attribute__((ext_vector_type(8)));
typedef _Float16 f16x4 __attribute__((ext_vector_type(4)));
typedef float f32x4 __attribute__((ext_vector_type(4)));

// Problem constants
#define BATCH 64
#define NTOK 785          // 1 + 28*28
#define CDIM 768
#define NHEAD 12
#define HDIM 64
#define ANUM 49
#define WIN 28
#define MROWS (BATCH * NTOK)   // 50240

// ---------------- workspace layout (bytes) ----------------
#define SZ_Q   77168640ULL                 // (B*H*N*64) halves
#define OFF_Q  0ULL
#define OFF_K  (OFF_Q + SZ_Q)
#define OFF_V  (OFF_K + SZ_Q)
#define OFF_Y  (OFF_V + SZ_Q)
#define OFF_VT (OFF_Y + SZ_Q)              // V transposed: (bh, d=64, n=800) f16
#define SZ_VT  78643200ULL
#define OFF_P  (OFF_VT + SZ_VT)            // P1 (bh,64,800) / P2 (bh,800,64) f16; also X16 / WP16 overlay
#define SZ_P   78643200ULL
#define OFF_AG (OFF_P + SZ_P)              // agent16: (bh, 64, 64) f16, scaled by 0.125
#define SZ_AG  6291456ULL
#define OFF_AVT (OFF_AG + SZ_AG)           // agentv^T: (bh, d=64, a=64) f16; also W16 overlay
#define OFF_B1 (OFF_AVT + SZ_AG)
#define SZ_B   1846320ULL
#define OFF_B2 (OFF_B1 + SZ_B)

#define GLL(g, l) __builtin_amdgcn_global_load_lds( \
    (const __attribute__((address_space(1))) void*)(g), \
    (__attribute__((address_space(3))) void*)(l), 16, 0, 0)

#define BAR()  asm volatile("s_barrier" ::: "memory")
#define VMW6() asm volatile("s_waitcnt vmcnt(6)" ::: "memory")
#define VMW0() asm volatile("s_waitcnt vmcnt(0)" ::: "memory")

// ---------------- fp32 -> fp16 conversion (x4 vectorized) -------------------
__global__ void cvt_kernel(const float* __restrict__ s, f16* __restrict__ d, int n4) {
    int i = blockIdx.x * 256 + threadIdx.x;
    if (i >= n4) return;
    float4 v = ((const float4*)s)[i];
    f16x4 o = {(f16)v.x, (f16)v.y, (f16)v.z, (f16)v.w};
    ((f16x4*)d)[i] = o;
}

// ---------------- bilinear (jax.image.resize, half-pixel centers, 7->28) ----
__device__ __forceinline__ float bilin7(const float* __restrict__ t, int y, int x) {
    float fy = 0.25f * (float)y - 0.375f;
    float fx = 0.25f * (float)x - 0.375f;
    int y0 = (int)floorf(fy);
    int x0 = (int)floorf(fx);
    float wy = fy - (float)y0, wx = fx - (float)x0;
    int y0c = max(0, min(6, y0)),     y1c = max(0, min(6, y0 + 1));
    int x0c = max(0, min(6, x0)),     x1c = max(0, min(6, x0 + 1));
    float v00 = t[y0c * 7 + x0c], v01 = t[y0c * 7 + x1c];
    float v10 = t[y1c * 7 + x0c], v11 = t[y1c * 7 + x1c];
    return (1.f - wy) * ((1.f - wx) * v00 + wx * v01) +
           wy        * ((1.f - wx) * v10 + wx * v11);
}

// ---------------- bias kernel: builds bias1[h][a][n] and bias2[h][n][a] -----
__global__ void bias_kernel(const float* __restrict__ an, const float* __restrict__ ah,
                            const float* __restrict__ aw, const float* __restrict__ ac,
                            const float* __restrict__ na, const float* __restrict__ ha,
                            const float* __restrict__ wa, const float* __restrict__ ca,
                            float* __restrict__ bias1, float* __restrict__ bias2) {
    int idx = blockIdx.x * 256 + threadIdx.x;
    const int total = NHEAD * ANUM * NTOK;
    if (idx >= total) return;
    int h = idx / (ANUM * NTOK);
    int r = idx % (ANUM * NTOK);
    int a = r / NTOK;
    int n = r % NTOK;
    float v1, v2;
    if (n == 0) {
        v1 = ac[h * ANUM + a];
        v2 = ca[h * ANUM + a];
    } else {
        int p = n - 1, y = p / WIN, x = p % WIN;
        int haidx = h * ANUM + a;
        v1 = bilin7(an + haidx * 49, y, x) + ah[haidx * WIN + y] + aw[haidx * WIN + x];
        v2 = bilin7(na + haidx * 49, y, x) + ha[(h * WIN + y) * ANUM + a] + wa[(h * WIN + x) * ANUM + a];
    }
    bias1[(h * ANUM + a) * NTOK + n] = v1;
    bias2[((size_t)h * NTOK + n) * ANUM + a] = v2;
}

// ============================================================================
// 256x128 MFMA GEMM core, 3-buffer / 2-tile-ahead pipeline.
// 512 threads = 8 waves (4 wm x 2 wn), each wave owns 64x64 output.
// BK=64, 12 K-tiles. LDS: 3 buffers x (A 32KB + B 16KB) = 144 KB.
// Per tile: 2 phases (kk=0, kk=1) of 16 MFMA each; 6 GLLs for tile t+2
// issued inside tile t's phases -> issue-to-wait distance >= 2 tile-times.
// Top-of-tile wait: vmcnt(6) (tile t+1's loads stay in flight; never 0
// until the last tile). Granule-XOR swizzle (slot s of row r holds global
// granule s^(r&7)): linear gload_lds dest + pre-swizzled source + same XOR
// on ds_read -> conflict-free ds_read_b128 (verified 0 conflicts in R3).
// ============================================================================
__device__ __forceinline__ void gemm_core_256x128(const f16* __restrict__ Ag,
                                                  const f16* __restrict__ Bg,
                                                  int m0, int n0, f16* sm,
                                                  f32x4 (&acc)[4][4]) {
    const int tid = threadIdx.x, w = tid >> 6, l = tid & 63;
    const int c = l & 15, q = l >> 4;
    const int wm = w >> 1, wn = w & 1;
    const int rl = l >> 3;                    // source row within 8-row unit
    const int gl = (l & 7) ^ (rl & 7);        // source granule for linear dest
    const f16* pA[4];
    const f16* pB[2];
#pragma unroll
    for (int j = 0; j < 4; ++j) {
        int ra = m0 + w * 32 + j * 8 + rl;
        ra = min(ra, MROWS - 1);
        pA[j] = Ag + (size_t)ra * CDIM + gl * 8;
    }
#pragma unroll
    for (int j = 0; j < 2; ++j)
        pB[j] = Bg + (size_t)(n0 + w * 16 + j * 8 + rl) * CDIM + gl * 8;

    const int gx0 = (q ^ (c & 7)) * 8;        // kk=0 granule slot
    const int gx1 = ((4 + q) ^ (c & 7)) * 8;  // kk=1
    const int laneA = (wm * 64 + c) * 64;     // f16 offset within A region
    const int laneB = 16384 + (wn * 64 + c) * 64;  // B region at +16384 f16

#pragma unroll
    for (int i = 0; i < 4; ++i)
#pragma unroll
        for (int j = 0; j < 4; ++j) acc[i][j] = (f32x4){0.f, 0.f, 0.f, 0.f};

    // buffer kt%3 at (kt%3)*24576 f16 (48 KB each)
    auto stageA = [&](int kt, int j) {
        int bb = (kt % 3) * 24576;
        GLL(pA[j] + (size_t)kt * 64, sm + bb + w * 2048 + j * 512);
    };
    auto stageB = [&](int kt, int j) {
        int bb = (kt % 3) * 24576;
        GLL(pB[j] + (size_t)kt * 64, sm + bb + 16384 + w * 1024 + j * 512);
    };

    // prologue: stage tiles 0 and 1 (12 loads in flight)
#pragma unroll
    for (int j = 0; j < 4; ++j) stageA(0, j);
#pragma unroll
    for (int j = 0; j < 2; ++j) stageB(0, j);
#pragma unroll
    for (int j = 0; j < 4; ++j) stageA(1, j);
#pragma unroll
    for (int j = 0; j < 2; ++j) stageB(1, j);

    for (int t = 0; t < 12; ++t) {
        const int sb = (t % 3) * 24576;
        if (t < 11) { VMW6(); } else { VMW0(); }   // tile t landed; t+1 in flight
        BAR();
        f16x8 af[4], bf[4];
        // ---- phase 0 (kk=0) ----
#pragma unroll
        for (int mf = 0; mf < 4; ++mf)
            af[mf] = *(const f16x8*)(sm + sb + laneA + mf * 16 * 64 + gx0);
#pragma unroll
        for (int nf = 0; nf < 4; ++nf)
            bf[nf] = *(const f16x8*)(sm + sb + laneB + nf * 16 * 64 + gx0);
        if (t < 10) { stageA(t + 2, 0); stageA(t + 2, 1); stageA(t + 2, 2); }
        BAR();
        __builtin_amdgcn_s_setprio(1);
#pragma unroll
        for (int mf = 0; mf < 4; ++mf)
#pragma unroll
            for (int nf = 0; nf < 4; ++nf)
                acc[mf][nf] = __builtin_amdgcn_mfma_f32_16x16x32_f16(
                    af[mf], bf[nf], acc[mf][nf], 0, 0, 0);
        __builtin_amdgcn_s_setprio(0);
        __builtin_amdgcn_sched_barrier(0);
        BAR();
        // ---- phase 1 (kk=1) ----
#pragma unroll
        for (int mf = 0; mf < 4; ++mf)
            af[mf] = *(const f16x8*)(sm + sb + laneA + mf * 16 * 64 + gx1);
#pragma unroll
        for (int nf = 0; nf < 4; ++nf)
            bf[nf] = *(const f16x8*)(sm + sb + laneB + nf * 16 * 64 + gx1);
        if (t < 10) { stageA(t + 2, 3); stageB(t + 2, 0); stageB(t + 2, 1); }
        BAR();
        __builtin_amdgcn_s_setprio(1);
#pragma unroll
        for (int mf = 0; mf < 4; ++mf)
#pragma unroll
            for (int nf = 0; nf < 4; ++nf)
                acc[mf][nf] = __builtin_amdgcn_mfma_f32_16x16x32_f16(
                    af[mf], bf[nf], acc[mf][nf], 0, 0, 0);
        __builtin_amdgcn_s_setprio(0);
        __builtin_amdgcn_sched_barrier(0);
        BAR();
    }
}

// ---------------- MFMA qkv GEMM: C = X16 @ W16^T, scatter f16 store --------
__global__ __launch_bounds__(512) void mfma_qkv(const f16* __restrict__ Ag,
                                                const f16* __restrict__ Bg,
                                                f16* __restrict__ qo,
                                                f16* __restrict__ ko,
                                                f16* __restrict__ vo,
                                                f16* __restrict__ vto) {
    __shared__ f16 sm[73728];  // 144 KB
    // nwg = 197*18 = 3546 = 8*443 + 2 (bijective XCD swizzle, m204)
    int bid = blockIdx.x;
    int xcd = bid & 7, sidx = bid >> 3;
    int wg = (xcd < 2 ? xcd * 444 : 2 * 444 + (xcd - 2) * 443) + sidx;
    int m0 = (wg / 18) * 256, n0 = (wg % 18) * 128;

    f32x4 acc[4][4];
    gemm_core_256x128(Ag, Bg, m0, n0, sm, acc);

    const int tid = threadIdx.x, w = tid >> 6, l = tid & 63;
    const int c = l & 15, q = l >> 4;
    const int wm = w >> 1, wn = w & 1;
    const int nb = n0 + wn * 64;          // 64-aligned -> single head slice
    const int tsel = nb / CDIM;
    const int h = (nb % CDIM) >> 6;
    f16* Ob = (tsel == 0) ? qo : (tsel == 1) ? ko : vo;
#pragma unroll
    for (int mf = 0; mf < 4; ++mf) {
#pragma unroll
        for (int r = 0; r < 4; ++r) {
            int m = m0 + wm * 64 + mf * 16 + q * 4 + r;
            if (m < MROWS) {
                int bb = m / NTOK;
                int nn = m - bb * NTOK;
                size_t ob = (((size_t)bb * NHEAD + h) * NTOK + nn) * HDIM;
#pragma unroll
                for (int nf = 0; nf < 4; ++nf) {
                    f16 v = (f16)acc[mf][nf][r];
                    Ob[ob + nf * 16 + c] = v;
                    if (tsel == 2)
                        vto[(((size_t)bb * NHEAD + h) * HDIM + nf * 16 + c) * 800 + nn] = v;
                }
            }
        }
    }
}

// ---------------- MFMA proj GEMM: D = Y16 @ WP16^T + bias (fp32 out) -------
__global__ __launch_bounds__(512) void mfma_proj(const f16* __restrict__ Ag,
                                                 const f16* __restrict__ Bg,
                                                 const float* __restrict__ bias,
                                                 float* __restrict__ D) {
    __shared__ f16 sm[73728];  // 144 KB
    // nwg = 197*6 = 1182 = 8*147 + 6
    int bid = blockIdx.x;
    int xcd = bid & 7, sidx = bid >> 3;
    int wg = (xcd < 6 ? xcd * 148 : 6 * 148 + (xcd - 6) * 147) + sidx;
    int m0 = (wg / 6) * 256, n0 = (wg % 6) * 128;

    f32x4 acc[4][4];
    gemm_core_256x128(Ag, Bg, m0, n0, sm, acc);

    const int tid = threadIdx.x, w = tid >> 6, l = tid & 63;
    const int c = l & 15, q = l >> 4;
    const int wm = w >> 1, wn = w & 1;
    const int nb = n0 + wn * 64;
    float bv[4];
#pragma unroll
    for (int nf = 0; nf < 4; ++nf) bv[nf] = bias[nb + nf * 16 + c];
#pragma unroll
    for (int mf = 0; mf < 4; ++mf) {
#pragma unroll
        for (int r = 0; r < 4; ++r) {
            int m = m0 + wm * 64 + mf * 16 + q * 4 + r;
            if (m < MROWS) {
                float* dp = D + (size_t)m * CDIM + nb;
#pragma unroll
                for (int nf = 0; nf < 4; ++nf)
                    dp[nf * 16 + c] = acc[mf][nf][r] + bv[nf];
            }
        }
    }
}

// ---------------- agent pooling -> agent16 (f16, pre-scaled by 0.125) ------
__global__ void pool_kernel(const f16* __restrict__ q16, f16* __restrict__ agent16) {
    int bidx = blockIdx.x;           // (b, h, a)
    int d = threadIdx.x;             // 64 threads
    int b = bidx / (NHEAD * ANUM);
    int r = bidx % (NHEAD * ANUM);
    int h = r / ANUM;
    int a = r % ANUM;
    int py = a / 7, px = a % 7;
    const f16* base = q16 + ((size_t)(b * NHEAD + h) * NTOK) * HDIM;
    float s = 0.f;
#pragma unroll
    for (int dy = 0; dy < 4; ++dy)
#pragma unroll
        for (int dx = 0; dx < 4; ++dx) {
            int n = 1 + (py * 4 + dy) * WIN + (px * 4 + dx);
            s += (float)base[(size_t)n * HDIM + d];
        }
    agent16[((size_t)(b * NHEAD + h) * 64 + a) * 64 + d] = (f16)(s * (1.0f / 16.0f) * 0.125f);
}

// ---------------- stage1 scores: S1 = agent16 . K^T + bias1 -> P (f16) -----
__global__ __launch_bounds__(256) void s1_score(const f16* __restrict__ k16,
                                                const f16* __restrict__ agent16,
                                                const float* __restrict__ bias1,
                                                f16* __restrict__ P) {
    int bh = blockIdx.x;
    int h = bh % NHEAD;
    int wid = threadIdx.x >> 6;
    int lane = threadIdx.x & 63;
    int quad = lane >> 4, col = lane & 15;
    const f16* ag = agent16 + (size_t)bh * 4096;
    f16x8 afr[4][2];
#pragma unroll
    for (int mt = 0; mt < 4; ++mt)
#pragma unroll
        for (int ks = 0; ks < 2; ++ks)
            afr[mt][ks] = *(const f16x8*)(ag + (mt * 16 + col) * 64 + ks * 32 + quad * 8);
    const f16* kb = k16 + (size_t)bh * (NTOK * HDIM);
    f16* Pb = P + (size_t)bh * (64 * 800);
    for (int nt = wid; nt < 50; nt += 4) {
        int nn = nt * 16 + col;
        f16x8 b0 = *(const f16x8*)(kb + (size_t)nn * 64 + quad * 8);
        f16x8 b1 = *(const f16x8*)(kb + (size_t)nn * 64 + 32 + quad * 8);
#pragma unroll
        for (int mt = 0; mt < 4; ++mt) {
            f32x4 cc = {0.f, 0.f, 0.f, 0.f};
            cc = __builtin_amdgcn_mfma_f32_16x16x32_f16(afr[mt][0], b0, cc, 0, 0, 0);
            cc = __builtin_amdgcn_mfma_f32_16x16x32_f16(afr[mt][1], b1, cc, 0, 0, 0);
#pragma unroll
            for (int r = 0; r < 4; ++r) {
                int a = mt * 16 + quad * 4 + r;
                float v = cc[r];
                if (a < ANUM && nn < NTOK) v += bias1[(h * ANUM + a) * NTOK + nn];
                Pb[(size_t)a * 800 + nn] = (f16)v;
            }
        }
    }
}

// ---------------- generic in-place row softmax over f16 buffer -------------
__global__ __launch_bounds__(256) void softmax16(f16* __restrict__ buf, int total_rows,
                                                 int rpb_valid, int rpb_alloc,
                                                 int valid, int stride) {
    int wid = threadIdx.x >> 6, lane = threadIdx.x & 63;
    int r = blockIdx.x * 4 + wid;
    if (r >= total_rows) return;
    int bh = r / rpb_valid, i0 = r % rpb_valid;
    f16* p = buf + ((size_t)bh * rpb_alloc + i0) * stride;
    float m = -1e30f;
    for (int i = lane; i < valid; i += 64) m = fmaxf(m, (float)p[i]);
#pragma unroll
    for (int off = 32; off > 0; off >>= 1) m = fmaxf(m, __shfl_xor(m, off));
    float s = 0.f;
    for (int i = lane; i < valid; i += 64) s += __expf((float)p[i] - m);
#pragma unroll
    for (int off = 32; off > 0; off >>= 1) s += __shfl_xor(s, off);
    float inv = 1.0f / s;
    for (int i = lane; i < stride; i += 64) {
        float v = (i < valid) ? __expf((float)p[i] - m) * inv : 0.f;
        p[i] = (f16)v;
    }
}

// ---------------- stage1 PV: agentv^T = (P1 . V)^T ------------------------
__global__ __launch_bounds__(256) void s1_pv(const f16* __restrict__ P,
                                             const f16* __restrict__ vT,
                                             f16* __restrict__ avT) {
    int bh = blockIdx.x;
    int wid = threadIdx.x >> 6;
    int lane = threadIdx.x & 63;
    int quad = lane >> 4, col = lane & 15;
    const f16* Pb = P + (size_t)bh * 51200;
    const f16* Vt = vT + (size_t)bh * 51200;
    int m0 = wid * 16;
    f32x4 acc0 = {0.f, 0.f, 0.f, 0.f}, acc1 = acc0, acc2 = acc0, acc3 = acc0;
    for (int ks = 0; ks < 25; ++ks) {
        int k0 = ks * 32 + quad * 8;
        f16x8 a  = *(const f16x8*)(Pb + (size_t)(m0 + col) * 800 + k0);
        f16x8 b0 = *(const f16x8*)(Vt + (size_t)(col) * 800 + k0);
        f16x8 b1 = *(const f16x8*)(Vt + (size_t)(16 + col) * 800 + k0);
        f16x8 b2 = *(const f16x8*)(Vt + (size_t)(32 + col) * 800 + k0);
        f16x8 b3 = *(const f16x8*)(Vt + (size_t)(48 + col) * 800 + k0);
        acc0 = __builtin_amdgcn_mfma_f32_16x16x32_f16(a, b0, acc0, 0, 0, 0);
        acc1 = __builtin_amdgcn_mfma_f32_16x16x32_f16(a, b1, acc1, 0, 0, 0);
        acc2 = __builtin_amdgcn_mfma_f32_16x16x32_f16(a, b2, acc2, 0, 0, 0);
        acc3 = __builtin_amdgcn_mfma_f32_16x16x32_f16(a, b3, acc3, 0, 0, 0);
    }
    f16* av = avT + (size_t)bh * 4096;
#pragma unroll
    for (int dt = 0; dt < 4; ++dt) {
        f32x4 acc = (dt == 0) ? acc0 : (dt == 1) ? acc1 : (dt == 2) ? acc2 : acc3;
        f16x4 o;
#pragma unroll
        for (int r = 0; r < 4; ++r) o[r] = (f16)acc[r];
        *(f16x4*)(av + (size_t)(dt * 16 + col) * 64 + m0 + quad * 4) = o;
    }
}

// ---------------- stage2 scores: S2 = q . agent16^T + bias2 -> P (f16) -----
__global__ __launch_bounds__(256) void s2_score(const f16* __restrict__ q16,
                                                const f16* __restrict__ agent16,
                                                const float* __restrict__ bias2,
                                                f16* __restrict__ P) {
    int bh = blockIdx.x;
    int h = bh % NHEAD;
    int wid = threadIdx.x >> 6, lane = threadIdx.x & 63;
    int quad = lane >> 4, col = lane & 15;
    int qt = blockIdx.y * 4 + wid;
    if (qt >= 50) return;
    int n0 = qt * 16;
    const f16* qb = q16 + (size_t)bh * (NTOK * HDIM);
    f16x8 a0 = *(const f16x8*)(qb + (size_t)(n0 + col) * 64 + quad * 8);
    f16x8 a1 = *(const f16x8*)(qb + (size_t)(n0 + col) * 64 + 32 + quad * 8);
    const f16* ag = agent16 + (size_t)bh * 4096;
    f16* Pb = P + (size_t)bh * 51200;
#pragma unroll
    for (int at = 0; at < 4; ++at) {
        f16x8 b0 = *(const f16x8*)(ag + (at * 16 + col) * 64 + quad * 8);
        f16x8 b1 = *(const f16x8*)(ag + (at * 16 + col) * 64 + 32 + quad * 8);
        f32x4 cc = {0.f, 0.f, 0.f, 0.f};
        cc = __builtin_amdgcn_mfma_f32_16x16x32_f16(a0, b0, cc, 0, 0, 0);
        cc = __builtin_amdgcn_mfma_f32_16x16x32_f16(a1, b1, cc, 0, 0, 0);
#pragma unroll
        for (int r = 0; r < 4; ++r) {
            int n = n0 + quad * 4 + r;
            int aa = at * 16 + col;
            float v = cc[r];
            if (n < NTOK && aa < ANUM) v += bias2[((size_t)h * NTOK + n) * ANUM + aa];
            Pb[(size_t)n * 64 + aa] = (f16)v;
        }
    }
}

// ---------------- stage2 out: y = P2 . agentv -----------------------------
__global__ __launch_bounds__(256) void s2_out(const f16* __restrict__ P,
                                              const f16* __restrict__ avT,
                                              f16* __restrict__ y16) {
    int bh = blockIdx.x;
    int b = bh / NHEAD, h = bh % NHEAD;
    int wid = threadIdx.x >> 6, lane = threadIdx.x & 63;
    int quad = lane >> 4, col = lane & 15;
    int qt = blockIdx.y * 4 + wid;
    if (qt >= 50) return;
    int n0 = qt * 16;
    const f16* Pb = P + (size_t)bh * 51200;
    f16x8 a0 = *(const f16x8*)(Pb + (size_t)(n0 + col) * 64 + quad * 8);
    f16x8 a1 = *(const f16x8*)(Pb + (size_t)(n0 + col) * 64 + 32 + quad * 8);
    const f16* av = avT + (size_t)bh * 4096;
#pragma unroll
    for (int dt = 0; dt < 4; ++dt) {
        f16x8 b0 = *(const f16x8*)(av + (dt * 16 + col) * 64 + quad * 8);
        f16x8 b1 = *(const f16x8*)(av + (dt * 16 + col) * 64 + 32 + quad * 8);
        f32x4 cc = {0.f, 0.f, 0.f, 0.f};
        cc = __builtin_amdgcn_mfma_f32_16x16x32_f16(a0, b0, cc, 0, 0, 0);
        cc = __builtin_amdgcn_mfma_f32_16x16x32_f16(a1, b1, cc, 0, 0, 0);
#pragma unroll
        for (int r = 0; r < 4; ++r) {
            int n = n0 + quad * 4 + r;
            if (n < NTOK)
                y16[((size_t)b * NTOK + n) * CDIM + h * HDIM + dt * 16 + col] = (f16)cc[r];
        }
    }
}

// ---------------- depthwise 3x3 conv on V image tokens, add into y ---------
__global__ void dwc_kernel(const f16* __restrict__ v16, const float* __restrict__ w,
                           const float* __restrict__ bias, f16* __restrict__ y16) {
    int c = blockIdx.x * 256 + threadIdx.x;  // 0..767
    int p = blockIdx.y;                      // 0..783
    int b = blockIdx.z;                      // 0..63
    int h = c >> 6, d = c & 63;
    int y = p / WIN, x = p % WIN;
    const f16* vb = v16 + ((size_t)(b * NHEAD + h) * NTOK) * HDIM + d;
    float acc = bias[c];
#pragma unroll
    for (int ky = 0; ky < 3; ++ky) {
        int yy = y + ky - 1;
        if (yy < 0 || yy >= WIN) continue;
#pragma unroll
        for (int kx = 0; kx < 3; ++kx) {
            int xx = x + kx - 1;
            if (xx < 0 || xx >= WIN) continue;
            int nn = 1 + yy * WIN + xx;
            acc += (float)vb[(size_t)nn * HDIM] * w[(ky * 3 + kx) * CDIM + c];
        }
    }
    size_t yi = ((size_t)b * NTOK + 1 + p) * CDIM + c;
    y16[yi] = (f16)((float)y16[yi] + acc);
}

// ---------------- launch ---------------------------------------------------
extern "C" void kernel_launch(void* const* d_in, const int* in_sizes, int n_in,
                              void* d_out, int out_size, void* d_ws, size_t ws_size,
                              hipStream_t stream) {
    const float* x      = (const float*)d_in[0];
    const float* w_qkv  = (const float*)d_in[1];
    const float* w_proj = (const float*)d_in[2];
    const float* b_proj = (const float*)d_in[3];
    const float* dwc_w  = (const float*)d_in[4];
    const float* dwc_b  = (const float*)d_in[5];
    const float* an     = (const float*)d_in[6];
    const float* ah     = (const float*)d_in[7];
    const float* aw     = (const float*)d_in[8];
    const float* na     = (const float*)d_in[9];
    const float* ha     = (const float*)d_in[10];
    const float* wa     = (const float*)d_in[11];
    const float* ac     = (const float*)d_in[12];
    const float* ca     = (const float*)d_in[13];
    float* out = (float*)d_out;

    char* ws = (char*)d_ws;
    f16* q16   = (f16*)(ws + OFF_Q);
    f16* k16   = (f16*)(ws + OFF_K);
    f16* v16   = (f16*)(ws + OFF_V);
    f16* y16   = (f16*)(ws + OFF_Y);
    f16* vT    = (f16*)(ws + OFF_VT);
    f16* Pbuf  = (f16*)(ws + OFF_P);
    f16* agent16 = (f16*)(ws + OFF_AG);
    f16* avT   = (f16*)(ws + OFF_AVT);
    float* bias1 = (float*)(ws + OFF_B1);
    float* bias2 = (float*)(ws + OFF_B2);
    // overlays (lifetime-disjoint)
    f16* X16  = (f16*)(ws + OFF_P);    // x in fp16, consumed by mfma_qkv before P is written
    f16* W16  = (f16*)(ws + OFF_AVT);  // w_qkv fp16, consumed before avT is written
    f16* WP16 = (f16*)(ws + OFF_P);    // w_proj fp16, written after P fully consumed

    bias_kernel<<<(NHEAD * ANUM * NTOK + 255) / 256, 256, 0, stream>>>(
        an, ah, aw, ac, na, ha, wa, ca, bias1, bias2);

    // fp32 -> fp16 conversions
    cvt_kernel<<<(MROWS * CDIM / 4 + 255) / 256, 256, 0, stream>>>(x, X16, MROWS * CDIM / 4);
    cvt_kernel<<<(3 * CDIM * CDIM / 4 + 255) / 256, 256, 0, stream>>>(w_qkv, W16, 3 * CDIM * CDIM / 4);

    // qkv GEMM (MFMA, 256x128 3-buf pipeline) -> q16/k16/v16 (head-major) + vT
    mfma_qkv<<<3546, 512, 0, stream>>>(X16, W16, q16, k16, v16, vT);

    pool_kernel<<<BATCH * NHEAD * ANUM, 64, 0, stream>>>(q16, agent16);

    // stage 1: scores -> softmax (in place) -> PV
    s1_score<<<BATCH * NHEAD, 256, 0, stream>>>(k16, agent16, bias1, Pbuf);
    softmax16<<<(BATCH * NHEAD * ANUM + 3) / 4, 256, 0, stream>>>(
        Pbuf, BATCH * NHEAD * ANUM, ANUM, 64, NTOK, 800);
    s1_pv<<<BATCH * NHEAD, 256, 0, stream>>>(Pbuf, vT, avT);

    // stage 2: scores -> softmax (in place) -> out (reuses Pbuf)
    s2_score<<<dim3(BATCH * NHEAD, 13), 256, 0, stream>>>(q16, agent16, bias2, Pbuf);
    softmax16<<<(BATCH * NHEAD * NTOK + 3) / 4, 256, 0, stream>>>(
        Pbuf, BATCH * NHEAD * NTOK, NTOK, 800, ANUM, 64);
    s2_out<<<dim3(BATCH * NHEAD, 13), 256, 0, stream>>>(Pbuf, avT, y16);

    dwc_kernel<<<dim3(CDIM / 256, WIN * WIN, BATCH), 256, 0, stream>>>(v16, dwc_w, dwc_b, y16);

    // output projection (MFMA, 256x128 3-buf pipeline)
    cvt_kernel<<<(CDIM * CDIM / 4 + 255) / 256, 256, 0, stream>>>(w_proj, WP16, CDIM * CDIM / 4);
    mfma_proj<<<1182, 512, 0, stream>>>(y16, WP16, b_proj, out);
}

// Round 5
// 1120.027 us; speedup vs baseline: 1.3293x; 1.2547x over previous
//
#include <hip/hip_runtime.h>
#include <hip/hip_fp16.h>

typedef _Float16 f16;
typedef _Float16 f16x8 __attribute__((ext_vector_type(8)));
typedef _Float16 f16x4 __attribute__((ext_vector_type(4)));
typedef float f32x4 __attribute__((ext_vector_type(4)));

// Problem constants
#define BATCH 64
#define NTOK 785          // 1 + 28*28
#define CDIM 768
#define NHEAD 12
#define HDIM 64
#define ANUM 49
#define WIN 28
#define MROWS (BATCH * NTOK)   // 50240

// ---------------- workspace layout (bytes) ----------------
#define SZ_Q   77168640ULL                 // (B*H*N*64) halves
#define OFF_Q  0ULL
#define OFF_K  (OFF_Q + SZ_Q)
#define OFF_V  (OFF_K + SZ_Q)
#define OFF_Y  (OFF_V + SZ_Q)
#define OFF_VT (OFF_Y + SZ_Q)              // V transposed: (bh, d=64, n=800) f16
#define SZ_VT  78643200ULL
#define OFF_P  (OFF_VT + SZ_VT)            // P1 (bh,64,800) f16; also X16 / WP16 overlay
#define SZ_P   78643200ULL
#define OFF_AG (OFF_P + SZ_P)              // agent16: (bh, 64, 64) f16, scaled by 0.125
#define SZ_AG  6291456ULL
#define OFF_AVT (OFF_AG + SZ_AG)           // agentv^T: (bh, d=64, a=64) f16; also W16 overlay
#define OFF_B1 (OFF_AVT + SZ_AG)
#define SZ_B   1846320ULL
#define OFF_B2 (OFF_B1 + SZ_B)

#define GLL(g, l) __builtin_amdgcn_global_load_lds( \
    (const __attribute__((address_space(1))) void*)(g), \
    (__attribute__((address_space(3))) void*)(l), 16, 0, 0)

#define BAR()  asm volatile("s_barrier" ::: "memory")
#define VMW6() asm volatile("s_waitcnt vmcnt(6)" ::: "memory")
#define VMW0() asm volatile("s_waitcnt vmcnt(0)" ::: "memory")

// ---------------- fp32 -> fp16 conversion (x4 vectorized) -------------------
__global__ void cvt_kernel(const float* __restrict__ s, f16* __restrict__ d, int n4) {
    int i = blockIdx.x * 256 + threadIdx.x;
    if (i >= n4) return;
    float4 v = ((const float4*)s)[i];
    f16x4 o = {(f16)v.x, (f16)v.y, (f16)v.z, (f16)v.w};
    ((f16x4*)d)[i] = o;
}

// ---------------- bilinear (jax.image.resize, half-pixel centers, 7->28) ----
__device__ __forceinline__ float bilin7(const float* __restrict__ t, int y, int x) {
    float fy = 0.25f * (float)y - 0.375f;
    float fx = 0.25f * (float)x - 0.375f;
    int y0 = (int)floorf(fy);
    int x0 = (int)floorf(fx);
    float wy = fy - (float)y0, wx = fx - (float)x0;
    int y0c = max(0, min(6, y0)),     y1c = max(0, min(6, y0 + 1));
    int x0c = max(0, min(6, x0)),     x1c = max(0, min(6, x0 + 1));
    float v00 = t[y0c * 7 + x0c], v01 = t[y0c * 7 + x1c];
    float v10 = t[y1c * 7 + x0c], v11 = t[y1c * 7 + x1c];
    return (1.f - wy) * ((1.f - wx) * v00 + wx * v01) +
           wy        * ((1.f - wx) * v10 + wx * v11);
}

// ---------------- bias kernel: builds bias1[h][a][n] and bias2[h][n][a] -----
__global__ void bias_kernel(const float* __restrict__ an, const float* __restrict__ ah,
                            const float* __restrict__ aw, const float* __restrict__ ac,
                            const float* __restrict__ na, const float* __restrict__ ha,
                            const float* __restrict__ wa, const float* __restrict__ ca,
                            float* __restrict__ bias1, float* __restrict__ bias2) {
    int idx = blockIdx.x * 256 + threadIdx.x;
    const int total = NHEAD * ANUM * NTOK;
    if (idx >= total) return;
    int h = idx / (ANUM * NTOK);
    int r = idx % (ANUM * NTOK);
    int a = r / NTOK;
    int n = r % NTOK;
    float v1, v2;
    if (n == 0) {
        v1 = ac[h * ANUM + a];
        v2 = ca[h * ANUM + a];
    } else {
        int p = n - 1, y = p / WIN, x = p % WIN;
        int haidx = h * ANUM + a;
        v1 = bilin7(an + haidx * 49, y, x) + ah[haidx * WIN + y] + aw[haidx * WIN + x];
        v2 = bilin7(na + haidx * 49, y, x) + ha[(h * WIN + y) * ANUM + a] + wa[(h * WIN + x) * ANUM + a];
    }
    bias1[(h * ANUM + a) * NTOK + n] = v1;
    bias2[((size_t)h * NTOK + n) * ANUM + a] = v2;
}

// ============================================================================
// 256x128 MFMA GEMM core, 3-buffer / 2-tile-ahead pipeline (R4, unchanged).
// ============================================================================
__device__ __forceinline__ void gemm_core_256x128(const f16* __restrict__ Ag,
                                                  const f16* __restrict__ Bg,
                                                  int m0, int n0, f16* sm,
                                                  f32x4 (&acc)[4][4]) {
    const int tid = threadIdx.x, w = tid >> 6, l = tid & 63;
    const int c = l & 15, q = l >> 4;
    const int wm = w >> 1, wn = w & 1;
    const int rl = l >> 3;                    // source row within 8-row unit
    const int gl = (l & 7) ^ (rl & 7);        // source granule for linear dest
    const f16* pA[4];
    const f16* pB[2];
#pragma unroll
    for (int j = 0; j < 4; ++j) {
        int ra = m0 + w * 32 + j * 8 + rl;
        ra = min(ra, MROWS - 1);
        pA[j] = Ag + (size_t)ra * CDIM + gl * 8;
    }
#pragma unroll
    for (int j = 0; j < 2; ++j)
        pB[j] = Bg + (size_t)(n0 + w * 16 + j * 8 + rl) * CDIM + gl * 8;

    const int gx0 = (q ^ (c & 7)) * 8;        // kk=0 granule slot
    const int gx1 = ((4 + q) ^ (c & 7)) * 8;  // kk=1
    const int laneA = (wm * 64 + c) * 64;     // f16 offset within A region
    const int laneB = 16384 + (wn * 64 + c) * 64;  // B region at +16384 f16

#pragma unroll
    for (int i = 0; i < 4; ++i)
#pragma unroll
        for (int j = 0; j < 4; ++j) acc[i][j] = (f32x4){0.f, 0.f, 0.f, 0.f};

    auto stageA = [&](int kt, int j) {
        int bb = (kt % 3) * 24576;
        GLL(pA[j] + (size_t)kt * 64, sm + bb + w * 2048 + j * 512);
    };
    auto stageB = [&](int kt, int j) {
        int bb = (kt % 3) * 24576;
        GLL(pB[j] + (size_t)kt * 64, sm + bb + 16384 + w * 1024 + j * 512);
    };

#pragma unroll
    for (int j = 0; j < 4; ++j) stageA(0, j);
#pragma unroll
    for (int j = 0; j < 2; ++j) stageB(0, j);
#pragma unroll
    for (int j = 0; j < 4; ++j) stageA(1, j);
#pragma unroll
    for (int j = 0; j < 2; ++j) stageB(1, j);

    for (int t = 0; t < 12; ++t) {
        const int sb = (t % 3) * 24576;
        if (t < 11) { VMW6(); } else { VMW0(); }
        BAR();
        f16x8 af[4], bf[4];
        // ---- phase 0 (kk=0) ----
#pragma unroll
        for (int mf = 0; mf < 4; ++mf)
            af[mf] = *(const f16x8*)(sm + sb + laneA + mf * 16 * 64 + gx0);
#pragma unroll
        for (int nf = 0; nf < 4; ++nf)
            bf[nf] = *(const f16x8*)(sm + sb + laneB + nf * 16 * 64 + gx0);
        if (t < 10) { stageA(t + 2, 0); stageA(t + 2, 1); stageA(t + 2, 2); }
        BAR();
        __builtin_amdgcn_s_setprio(1);
#pragma unroll
        for (int mf = 0; mf < 4; ++mf)
#pragma unroll
            for (int nf = 0; nf < 4; ++nf)
                acc[mf][nf] = __builtin_amdgcn_mfma_f32_16x16x32_f16(
                    af[mf], bf[nf], acc[mf][nf], 0, 0, 0);
        __builtin_amdgcn_s_setprio(0);
        __builtin_amdgcn_sched_barrier(0);
        BAR();
        // ---- phase 1 (kk=1) ----
#pragma unroll
        for (int mf = 0; mf < 4; ++mf)
            af[mf] = *(const f16x8*)(sm + sb + laneA + mf * 16 * 64 + gx1);
#pragma unroll
        for (int nf = 0; nf < 4; ++nf)
            bf[nf] = *(const f16x8*)(sm + sb + laneB + nf * 16 * 64 + gx1);
        if (t < 10) { stageA(t + 2, 3); stageB(t + 2, 0); stageB(t + 2, 1); }
        BAR();
        __builtin_amdgcn_s_setprio(1);
#pragma unroll
        for (int mf = 0; mf < 4; ++mf)
#pragma unroll
            for (int nf = 0; nf < 4; ++nf)
                acc[mf][nf] = __builtin_amdgcn_mfma_f32_16x16x32_f16(
                    af[mf], bf[nf], acc[mf][nf], 0, 0, 0);
        __builtin_amdgcn_s_setprio(0);
        __builtin_amdgcn_sched_barrier(0);
        BAR();
    }
}

// ---------------- MFMA qkv GEMM: C = X16 @ W16^T, scatter f16 store --------
__global__ __launch_bounds__(512) void mfma_qkv(const f16* __restrict__ Ag,
                                                const f16* __restrict__ Bg,
                                                f16* __restrict__ qo,
                                                f16* __restrict__ ko,
                                                f16* __restrict__ vo,
                                                f16* __restrict__ vto) {
    __shared__ f16 sm[73728];  // 144 KB
    // nwg = 197*18 = 3546 = 8*443 + 2 (bijective XCD swizzle, m204)
    int bid = blockIdx.x;
    int xcd = bid & 7, sidx = bid >> 3;
    int wg = (xcd < 2 ? xcd * 444 : 2 * 444 + (xcd - 2) * 443) + sidx;
    int m0 = (wg / 18) * 256, n0 = (wg % 18) * 128;

    f32x4 acc[4][4];
    gemm_core_256x128(Ag, Bg, m0, n0, sm, acc);

    const int tid = threadIdx.x, w = tid >> 6, l = tid & 63;
    const int c = l & 15, q = l >> 4;
    const int wm = w >> 1, wn = w & 1;
    const int nb = n0 + wn * 64;          // 64-aligned -> single head slice
    const int tsel = nb / CDIM;
    const int h = (nb % CDIM) >> 6;
    f16* Ob = (tsel == 0) ? qo : (tsel == 1) ? ko : vo;
#pragma unroll
    for (int mf = 0; mf < 4; ++mf) {
#pragma unroll
        for (int r = 0; r < 4; ++r) {
            int m = m0 + wm * 64 + mf * 16 + q * 4 + r;
            if (m < MROWS) {
                int bb = m / NTOK;
                int nn = m - bb * NTOK;
                size_t ob = (((size_t)bb * NHEAD + h) * NTOK + nn) * HDIM;
#pragma unroll
                for (int nf = 0; nf < 4; ++nf) {
                    f16 v = (f16)acc[mf][nf][r];
                    Ob[ob + nf * 16 + c] = v;
                    if (tsel == 2)
                        vto[(((size_t)bb * NHEAD + h) * HDIM + nf * 16 + c) * 800 + nn] = v;
                }
            }
        }
    }
}

// ---------------- MFMA proj GEMM: D = Y16 @ WP16^T + bias (fp32 out) -------
__global__ __launch_bounds__(512) void mfma_proj(const f16* __restrict__ Ag,
                                                 const f16* __restrict__ Bg,
                                                 const float* __restrict__ bias,
                                                 float* __restrict__ D) {
    __shared__ f16 sm[73728];  // 144 KB
    // nwg = 197*6 = 1182 = 8*147 + 6
    int bid = blockIdx.x;
    int xcd = bid & 7, sidx = bid >> 3;
    int wg = (xcd < 6 ? xcd * 148 : 6 * 148 + (xcd - 6) * 147) + sidx;
    int m0 = (wg / 6) * 256, n0 = (wg % 6) * 128;

    f32x4 acc[4][4];
    gemm_core_256x128(Ag, Bg, m0, n0, sm, acc);

    const int tid = threadIdx.x, w = tid >> 6, l = tid & 63;
    const int c = l & 15, q = l >> 4;
    const int wm = w >> 1, wn = w & 1;
    const int nb = n0 + wn * 64;
    float bv[4];
#pragma unroll
    for (int nf = 0; nf < 4; ++nf) bv[nf] = bias[nb + nf * 16 + c];
#pragma unroll
    for (int mf = 0; mf < 4; ++mf) {
#pragma unroll
        for (int r = 0; r < 4; ++r) {
            int m = m0 + wm * 64 + mf * 16 + q * 4 + r;
            if (m < MROWS) {
                float* dp = D + (size_t)m * CDIM + nb;
#pragma unroll
                for (int nf = 0; nf < 4; ++nf)
                    dp[nf * 16 + c] = acc[mf][nf][r] + bv[nf];
            }
        }
    }
}

// ---------------- agent pooling -> agent16 (f16, pre-scaled by 0.125) ------
__global__ void pool_kernel(const f16* __restrict__ q16, f16* __restrict__ agent16) {
    int bidx = blockIdx.x;           // (b, h, a)
    int d = threadIdx.x;             // 64 threads
    int b = bidx / (NHEAD * ANUM);
    int r = bidx % (NHEAD * ANUM);
    int h = r / ANUM;
    int a = r % ANUM;
    int py = a / 7, px = a % 7;
    const f16* base = q16 + ((size_t)(b * NHEAD + h) * NTOK) * HDIM;
    float s = 0.f;
#pragma unroll
    for (int dy = 0; dy < 4; ++dy)
#pragma unroll
        for (int dx = 0; dx < 4; ++dx) {
            int n = 1 + (py * 4 + dy) * WIN + (px * 4 + dx);
            s += (float)base[(size_t)n * HDIM + d];
        }
    agent16[((size_t)(b * NHEAD + h) * 64 + a) * 64 + d] = (f16)(s * (1.0f / 16.0f) * 0.125f);
}

// ---------------- stage1 scores: S1 = agent16 . K^T + bias1 -> P (f16) -----
__global__ __launch_bounds__(256) void s1_score(const f16* __restrict__ k16,
                                                const f16* __restrict__ agent16,
                                                const float* __restrict__ bias1,
                                                f16* __restrict__ P) {
    int bh = blockIdx.x;
    int h = bh % NHEAD;
    int wid = threadIdx.x >> 6;
    int lane = threadIdx.x & 63;
    int quad = lane >> 4, col = lane & 15;
    const f16* ag = agent16 + (size_t)bh * 4096;
    f16x8 afr[4][2];
#pragma unroll
    for (int mt = 0; mt < 4; ++mt)
#pragma unroll
        for (int ks = 0; ks < 2; ++ks)
            afr[mt][ks] = *(const f16x8*)(ag + (mt * 16 + col) * 64 + ks * 32 + quad * 8);
    const f16* kb = k16 + (size_t)bh * (NTOK * HDIM);
    f16* Pb = P + (size_t)bh * (64 * 800);
    for (int nt = wid; nt < 50; nt += 4) {
        int nn = nt * 16 + col;
        f16x8 b0 = *(const f16x8*)(kb + (size_t)nn * 64 + quad * 8);
        f16x8 b1 = *(const f16x8*)(kb + (size_t)nn * 64 + 32 + quad * 8);
#pragma unroll
        for (int mt = 0; mt < 4; ++mt) {
            f32x4 cc = {0.f, 0.f, 0.f, 0.f};
            cc = __builtin_amdgcn_mfma_f32_16x16x32_f16(afr[mt][0], b0, cc, 0, 0, 0);
            cc = __builtin_amdgcn_mfma_f32_16x16x32_f16(afr[mt][1], b1, cc, 0, 0, 0);
#pragma unroll
            for (int r = 0; r < 4; ++r) {
                int a = mt * 16 + quad * 4 + r;
                float v = cc[r];
                if (a < ANUM && nn < NTOK) v += bias1[(h * ANUM + a) * NTOK + nn];
                Pb[(size_t)a * 800 + nn] = (f16)v;
            }
        }
    }
}

// ---------------- generic in-place row softmax over f16 buffer (stage1) ----
__global__ __launch_bounds__(256) void softmax16(f16* __restrict__ buf, int total_rows,
                                                 int rpb_valid, int rpb_alloc,
                                                 int valid, int stride) {
    int wid = threadIdx.x >> 6, lane = threadIdx.x & 63;
    int r = blockIdx.x * 4 + wid;
    if (r >= total_rows) return;
    int bh = r / rpb_valid, i0 = r % rpb_valid;
    f16* p = buf + ((size_t)bh * rpb_alloc + i0) * stride;
    float m = -1e30f;
    for (int i = lane; i < valid; i += 64) m = fmaxf(m, (float)p[i]);
#pragma unroll
    for (int off = 32; off > 0; off >>= 1) m = fmaxf(m, __shfl_xor(m, off));
    float s = 0.f;
    for (int i = lane; i < valid; i += 64) s += __expf((float)p[i] - m);
#pragma unroll
    for (int off = 32; off > 0; off >>= 1) s += __shfl_xor(s, off);
    float inv = 1.0f / s;
    for (int i = lane; i < stride; i += 64) {
        float v = (i < valid) ? __expf((float)p[i] - m) * inv : 0.f;
        p[i] = (f16)v;
    }
}

// ---------------- stage1 PV: agentv^T = (P1 . V)^T ------------------------
__global__ __launch_bounds__(256) void s1_pv(const f16* __restrict__ P,
                                             const f16* __restrict__ vT,
                                             f16* __restrict__ avT) {
    int bh = blockIdx.x;
    int wid = threadIdx.x >> 6;
    int lane = threadIdx.x & 63;
    int quad = lane >> 4, col = lane & 15;
    const f16* Pb = P + (size_t)bh * 51200;
    const f16* Vt = vT + (size_t)bh * 51200;
    int m0 = wid * 16;
    f32x4 acc0 = {0.f, 0.f, 0.f, 0.f}, acc1 = acc0, acc2 = acc0, acc3 = acc0;
    for (int ks = 0; ks < 25; ++ks) {
        int k0 = ks * 32 + quad * 8;
        f16x8 a  = *(const f16x8*)(Pb + (size_t)(m0 + col) * 800 + k0);
        f16x8 b0 = *(const f16x8*)(Vt + (size_t)(col) * 800 + k0);
        f16x8 b1 = *(const f16x8*)(Vt + (size_t)(16 + col) * 800 + k0);
        f16x8 b2 = *(const f16x8*)(Vt + (size_t)(32 + col) * 800 + k0);
        f16x8 b3 = *(const f16x8*)(Vt + (size_t)(48 + col) * 800 + k0);
        acc0 = __builtin_amdgcn_mfma_f32_16x16x32_f16(a, b0, acc0, 0, 0, 0);
        acc1 = __builtin_amdgcn_mfma_f32_16x16x32_f16(a, b1, acc1, 0, 0, 0);
        acc2 = __builtin_amdgcn_mfma_f32_16x16x32_f16(a, b2, acc2, 0, 0, 0);
        acc3 = __builtin_amdgcn_mfma_f32_16x16x32_f16(a, b3, acc3, 0, 0, 0);
    }
    f16* av = avT + (size_t)bh * 4096;
#pragma unroll
    for (int dt = 0; dt < 4; ++dt) {
        f32x4 acc = (dt == 0) ? acc0 : (dt == 1) ? acc1 : (dt == 2) ? acc2 : acc3;
        f16x4 o;
#pragma unroll
        for (int r = 0; r < 4; ++r) o[r] = (f16)acc[r];
        *(f16x4*)(av + (size_t)(dt * 16 + col) * 64 + m0 + quad * 4) = o;
    }
}

// ---------------- fused stage2: scores + row-softmax + PV + store ----------
// grid (768, 13), 256 thr = 4 waves; wave handles 16 q-rows.
// Scores: C-frag holds row=quad*4+r (16 rows), agent=at*16+col.
// Softmax over agents: per-row reduce across col lanes via shfl_xor(1,2,4,8)
// (stays within quad group) x 4 at-regs; invalid agents (>=49) excluded.
// P -> A-frag transpose via 9 KB wave-private LDS bounce, then PV MFMAs.
__global__ __launch_bounds__(256) void fused_s2(const f16* __restrict__ q16,
                                                const f16* __restrict__ agent16,
                                                const float* __restrict__ bias2,
                                                const f16* __restrict__ avT,
                                                f16* __restrict__ y16) {
    __shared__ f16 pl[4][16][72];  // [wave][row][agent] (+pad)
    int bh = blockIdx.x;
    int b = bh / NHEAD, h = bh % NHEAD;
    int wid = threadIdx.x >> 6, lane = threadIdx.x & 63;
    int quad = lane >> 4, col = lane & 15;
    int qt = blockIdx.y * 4 + wid;
    if (qt >= 50) return;
    int n0 = qt * 16;
    const f16* qb = q16 + (size_t)bh * (NTOK * HDIM);
    f16x8 a0 = *(const f16x8*)(qb + (size_t)(n0 + col) * 64 + quad * 8);
    f16x8 a1 = *(const f16x8*)(qb + (size_t)(n0 + col) * 64 + 32 + quad * 8);
    const f16* ag = agent16 + (size_t)bh * 4096;

    // scores + bias, kept in registers: v[at][r]
    float sv[4][4];
#pragma unroll
    for (int at = 0; at < 4; ++at) {
        f16x8 b0 = *(const f16x8*)(ag + (at * 16 + col) * 64 + quad * 8);
        f16x8 b1 = *(const f16x8*)(ag + (at * 16 + col) * 64 + 32 + quad * 8);
        f32x4 cc = {0.f, 0.f, 0.f, 0.f};
        cc = __builtin_amdgcn_mfma_f32_16x16x32_f16(a0, b0, cc, 0, 0, 0);
        cc = __builtin_amdgcn_mfma_f32_16x16x32_f16(a1, b1, cc, 0, 0, 0);
        int aa = at * 16 + col;
#pragma unroll
        for (int r = 0; r < 4; ++r) {
            int n = n0 + quad * 4 + r;
            float v = -1e30f;  // invalid agent -> excluded from max/sum
            if (aa < ANUM) {
                v = cc[r];
                if (n < NTOK) v += bias2[((size_t)h * NTOK + n) * ANUM + aa];
            }
            sv[at][r] = v;
        }
    }
    // row softmax over agent dim (per r: reduce over 4 at-regs x 16 col lanes)
#pragma unroll
    for (int r = 0; r < 4; ++r) {
        float m = fmaxf(fmaxf(sv[0][r], sv[1][r]), fmaxf(sv[2][r], sv[3][r]));
#pragma unroll
        for (int off = 8; off > 0; off >>= 1) m = fmaxf(m, __shfl_xor(m, off));
        float e0 = (sv[0][r] > -1e29f) ? __expf(sv[0][r] - m) : 0.f;
        float e1 = (sv[1][r] > -1e29f) ? __expf(sv[1][r] - m) : 0.f;
        float e2 = (sv[2][r] > -1e29f) ? __expf(sv[2][r] - m) : 0.f;
        float e3 = (sv[3][r] > -1e29f) ? __expf(sv[3][r] - m) : 0.f;
        float s = e0 + e1 + e2 + e3;
#pragma unroll
        for (int off = 8; off > 0; off >>= 1) s += __shfl_xor(s, off);
        float inv = 1.0f / s;
        sv[0][r] = e0 * inv; sv[1][r] = e1 * inv; sv[2][r] = e2 * inv; sv[3][r] = e3 * inv;
    }
    // bounce P to LDS (wave-private) to re-fragment as MFMA A-operand
#pragma unroll
    for (int at = 0; at < 4; ++at)
#pragma unroll
        for (int r = 0; r < 4; ++r)
            pl[wid][quad * 4 + r][at * 16 + col] = (f16)sv[at][r];
    asm volatile("s_waitcnt lgkmcnt(0)" ::: "memory");
    f16x8 pa0 = *(const f16x8*)(&pl[wid][col][0] + quad * 8);
    f16x8 pa1 = *(const f16x8*)(&pl[wid][col][0] + 32 + quad * 8);

    const f16* av = avT + (size_t)bh * 4096;
#pragma unroll
    for (int dt = 0; dt < 4; ++dt) {
        f16x8 b0 = *(const f16x8*)(av + (dt * 16 + col) * 64 + quad * 8);
        f16x8 b1 = *(const f16x8*)(av + (dt * 16 + col) * 64 + 32 + quad * 8);
        f32x4 cc = {0.f, 0.f, 0.f, 0.f};
        cc = __builtin_amdgcn_mfma_f32_16x16x32_f16(pa0, b0, cc, 0, 0, 0);
        cc = __builtin_amdgcn_mfma_f32_16x16x32_f16(pa1, b1, cc, 0, 0, 0);
#pragma unroll
        for (int r = 0; r < 4; ++r) {
            int n = n0 + quad * 4 + r;
            if (n < NTOK)
                y16[((size_t)b * NTOK + n) * CDIM + h * HDIM + dt * 16 + col] = (f16)cc[r];
        }
    }
}

// ---------------- depthwise 3x3 conv, sliding-window, add into y -----------
// grid (WIN, BATCH) x 768 thr: thread = channel c, walks x with 3x3 window.
__global__ __launch_bounds__(768) void dwc_kernel(const f16* __restrict__ v16,
                                                  const float* __restrict__ w,
                                                  const float* __restrict__ bias,
                                                  f16* __restrict__ y16) {
    int y = blockIdx.x;                      // 0..27
    int b = blockIdx.y;                      // 0..63
    int c = threadIdx.x;                     // 0..767
    int h = c >> 6, d = c & 63;
    const f16* vb = v16 + ((size_t)(b * NHEAD + h) * NTOK) * HDIM + d;
    float wr[9];
#pragma unroll
    for (int k = 0; k < 9; ++k) wr[k] = w[k * CDIM + c];
    float bias_c = bias[c];
    bool rok[3] = { y - 1 >= 0, true, y + 1 < WIN };
    int rbase[3] = { (y - 1) * WIN, y * WIN, (y + 1) * WIN };

    // window col j holds input column (x-1+j); init for x=0
    float win[3][3];
#pragma unroll
    for (int ky = 0; ky < 3; ++ky) {
        win[0][ky] = 0.f;
        win[1][ky] = rok[ky] ? (float)vb[(size_t)(1 + rbase[ky] + 0) * HDIM] : 0.f;
        win[2][ky] = rok[ky] ? (float)vb[(size_t)(1 + rbase[ky] + 1) * HDIM] : 0.f;
    }
    for (int x = 0; x < WIN; ++x) {
        float acc = bias_c;
#pragma unroll
        for (int ky = 0; ky < 3; ++ky)
#pragma unroll
            for (int j = 0; j < 3; ++j)
                acc += win[j][ky] * wr[ky * 3 + j];
        size_t yi = ((size_t)b * NTOK + 1 + y * WIN + x) * CDIM + c;
        y16[yi] = (f16)((float)y16[yi] + acc);
        // shift window, load column x+2
#pragma unroll
        for (int ky = 0; ky < 3; ++ky) {
            win[0][ky] = win[1][ky];
            win[1][ky] = win[2][ky];
            win[2][ky] = (x + 2 < WIN && rok[ky])
                         ? (float)vb[(size_t)(1 + rbase[ky] + x + 2) * HDIM] : 0.f;
        }
    }
}

// ---------------- launch ---------------------------------------------------
extern "C" void kernel_launch(void* const* d_in, const int* in_sizes, int n_in,
                              void* d_out, int out_size, void* d_ws, size_t ws_size,
                              hipStream_t stream) {
    const float* x      = (const float*)d_in[0];
    const float* w_qkv  = (const float*)d_in[1];
    const float* w_proj = (const float*)d_in[2];
    const float* b_proj = (const float*)d_in[3];
    const float* dwc_w  = (const float*)d_in[4];
    const float* dwc_b  = (const float*)d_in[5];
    const float* an     = (const float*)d_in[6];
    const float* ah     = (const float*)d_in[7];
    const float* aw     = (const float*)d_in[8];
    const float* na     = (const float*)d_in[9];
    const float* ha     = (const float*)d_in[10];
    const float* wa     = (const float*)d_in[11];
    const float* ac     = (const float*)d_in[12];
    const float* ca     = (const float*)d_in[13];
    float* out = (float*)d_out;

    char* ws = (char*)d_ws;
    f16* q16   = (f16*)(ws + OFF_Q);
    f16* k16   = (f16*)(ws + OFF_K);
    f16* v16   = (f16*)(ws + OFF_V);
    f16* y16   = (f16*)(ws + OFF_Y);
    f16* vT    = (f16*)(ws + OFF_VT);
    f16* Pbuf  = (f16*)(ws + OFF_P);
    f16* agent16 = (f16*)(ws + OFF_AG);
    f16* avT   = (f16*)(ws + OFF_AVT);
    float* bias1 = (float*)(ws + OFF_B1);
    float* bias2 = (float*)(ws + OFF_B2);
    // overlays (lifetime-disjoint)
    f16* X16  = (f16*)(ws + OFF_P);    // x in fp16, consumed by mfma_qkv before P is written
    f16* W16  = (f16*)(ws + OFF_AVT);  // w_qkv fp16, consumed before avT is written
    f16* WP16 = (f16*)(ws + OFF_P);    // w_proj fp16, written after P1 fully consumed

    bias_kernel<<<(NHEAD * ANUM * NTOK + 255) / 256, 256, 0, stream>>>(
        an, ah, aw, ac, na, ha, wa, ca, bias1, bias2);

    // fp32 -> fp16 conversions
    cvt_kernel<<<(MROWS * CDIM / 4 + 255) / 256, 256, 0, stream>>>(x, X16, MROWS * CDIM / 4);
    cvt_kernel<<<(3 * CDIM * CDIM / 4 + 255) / 256, 256, 0, stream>>>(w_qkv, W16, 3 * CDIM * CDIM / 4);

    // qkv GEMM (MFMA, 256x128 3-buf pipeline) -> q16/k16/v16 (head-major) + vT
    mfma_qkv<<<3546, 512, 0, stream>>>(X16, W16, q16, k16, v16, vT);

    pool_kernel<<<BATCH * NHEAD * ANUM, 64, 0, stream>>>(q16, agent16);

    // stage 1: scores -> softmax (in place) -> PV
    s1_score<<<BATCH * NHEAD, 256, 0, stream>>>(k16, agent16, bias1, Pbuf);
    softmax16<<<(BATCH * NHEAD * ANUM + 3) / 4, 256, 0, stream>>>(
        Pbuf, BATCH * NHEAD * ANUM, ANUM, 64, NTOK, 800);
    s1_pv<<<BATCH * NHEAD, 256, 0, stream>>>(Pbuf, vT, avT);

    // stage 2: fused scores + softmax + PV + store
    fused_s2<<<dim3(BATCH * NHEAD, 13), 256, 0, stream>>>(q16, agent16, bias2, avT, y16);

    dwc_kernel<<<dim3(WIN, BATCH), 768, 0, stream>>>(v16, dwc_w, dwc_b, y16);

    // output projection (MFMA, 256x128 3-buf pipeline)
    cvt_kernel<<<(CDIM * CDIM / 4 + 255) / 256, 256, 0, stream>>>(w_proj, WP16, CDIM * CDIM / 4);
    mfma_proj<<<1182, 512, 0, stream>>>(y16, WP16, b_proj, out);
}